// Round 2
// baseline (44514.737 us; speedup 1.0000x reference)
//
#include <hip/hip_runtime.h>
#include <hip/hip_bf16.h>
#include <hip/hip_cooperative_groups.h>

namespace cg = cooperative_groups;

typedef __bf16 bf16x8 __attribute__((ext_vector_type(8)));
typedef float  f32x4  __attribute__((ext_vector_type(4)));

#define MFMA16(a, b, c) __builtin_amdgcn_mfma_f32_16x16x32_bf16((a), (b), (c), 0, 0, 0)

static constexpr int Bz = 64, Tz = 512, Dz = 512, Hz = 1024;
static constexpr int NWG = 128;   // each WG owns NJ h-columns
static constexpr int NJ  = 8;

// ws layout, in bf16 elements
static constexpr size_t N_W0X  = 4096ull * 512;
static constexpr size_t N_W0H  = 4096ull * 1024;
static constexpr size_t N_W1   = 4096ull * 2048;
static constexpr size_t OFF_W0XH = 0;
static constexpr size_t OFF_W0XL = OFF_W0XH + N_W0X;
static constexpr size_t OFF_W0H  = OFF_W0XL + N_W0X;
static constexpr size_t OFF_W1   = OFF_W0H  + N_W0H;
static constexpr size_t OFF_Y0   = OFF_W1   + N_W1;     // [64][512][1024] bf16
// total: (2*2.1M + 4.2M + 8.4M + 33.6M) * 2B ~= 100.7 MB

__device__ __forceinline__ float sigm(float x) { return 1.0f / (1.0f + __expf(-x)); }

// ---------------- prep: split/cast weights to bf16 in ws ----------------
extern "C" __global__ void prep_split(const float* __restrict__ W0,
                                      const float* __restrict__ W1,
                                      __bf16* __restrict__ ws)
{
    __bf16* w0xh = ws + OFF_W0XH;
    __bf16* w0xl = ws + OFF_W0XL;
    __bf16* w0h  = ws + OFF_W0H;
    __bf16* w1c  = ws + OFF_W1;
    const size_t ntot = N_W0X + N_W0H + N_W1;
    for (size_t idx = (size_t)blockIdx.x * blockDim.x + threadIdx.x;
         idx < ntot; idx += (size_t)gridDim.x * blockDim.x) {
        if (idx < N_W0X) {
            size_t r = idx >> 9, c = idx & 511;           // /512, %512
            float w = W0[r * 1536 + c];
            __bf16 hi = (__bf16)w;
            w0xh[idx] = hi;
            w0xl[idx] = (__bf16)(w - (float)hi);
        } else if (idx < N_W0X + N_W0H) {
            size_t i = idx - N_W0X;
            size_t r = i >> 10, c = i & 1023;             // /1024, %1024
            w0h[i] = (__bf16)W0[r * 1536 + 512 + c];
        } else {
            size_t i = idx - N_W0X - N_W0H;
            w1c[i] = (__bf16)W1[i];
        }
    }
}

// ---------------- layer 0: x f32 (split on the fly), h bf16 (y0) ----------------
__device__ __forceinline__ void layer0(
    const float* __restrict__ x,
    const __bf16* __restrict__ w0xh, const __bf16* __restrict__ w0xl,
    const __bf16* __restrict__ w0h,  const float* __restrict__ b0,
    __bf16* y0, float* zbuf, cg::grid_group& grid)
{
    const int tid  = threadIdx.x;
    const int wave = tid >> 6, lane = tid & 63, l15 = lane & 15, lg = lane >> 4;
    const int j0   = blockIdx.x * NJ;

    const __bf16* wxh[2]; const __bf16* wxl[2]; const __bf16* whp[2]; float bv[2];
#pragma unroll
    for (int tn = 0; tn < 2; ++tn) {
        int c = tn * 16 + l15, gate = c >> 3, j = c & 7;
        int row = gate * Hz + j0 + j;
        wxh[tn] = w0xh + (size_t)row * Dz + lg * 8;
        wxl[tn] = w0xl + (size_t)row * Dz + lg * 8;
        whp[tn] = w0h  + (size_t)row * Hz + lg * 8;
        bv[tn]  = b0[row];
    }
    const int bA = wave * 16 + l15;
    const float*  xp = x  + (size_t)bA * Tz * Dz + lg * 8;
    const __bf16* hp = y0 + (size_t)bA * Tz * Hz + lg * 8;

    const int idx0 = tid * 2, idx1 = idx0 + 1;
    const int gB0 = idx0 >> 3, gJ0 = idx0 & 7, gB1 = idx1 >> 3, gJ1 = idx1 & 7;
    float cs0 = 0.f, cs1 = 0.f;

    for (int t = 0; t < Tz; ++t) {
        f32x4 ax0 = {0,0,0,0}, ax1 = {0,0,0,0}, ah0 = {0,0,0,0}, ah1 = {0,0,0,0};

        const float* xt = xp + (size_t)t * Dz;
#pragma unroll 4
        for (int kk = 0; kk < Dz / 32; ++kk) {
            f32x4 va = *(const f32x4*)(xt + kk * 32);
            f32x4 vb = *(const f32x4*)(xt + kk * 32 + 4);
            bf16x8 ahi, alo;
#pragma unroll
            for (int e = 0; e < 4; ++e) {
                float v = va[e]; __bf16 h1 = (__bf16)v;
                ahi[e] = h1; alo[e] = (__bf16)(v - (float)h1);
                float w = vb[e]; __bf16 h2 = (__bf16)w;
                ahi[4 + e] = h2; alo[4 + e] = (__bf16)(w - (float)h2);
            }
            bf16x8 wh0 = *(const bf16x8*)(wxh[0] + kk * 32);
            bf16x8 wl0 = *(const bf16x8*)(wxl[0] + kk * 32);
            bf16x8 wh1 = *(const bf16x8*)(wxh[1] + kk * 32);
            bf16x8 wl1 = *(const bf16x8*)(wxl[1] + kk * 32);
            ax0 = MFMA16(ahi, wh0, ax0); ax0 = MFMA16(alo, wh0, ax0); ax0 = MFMA16(ahi, wl0, ax0);
            ax1 = MFMA16(ahi, wh1, ax1); ax1 = MFMA16(alo, wh1, ax1); ax1 = MFMA16(ahi, wl1, ax1);
        }
        if (t > 0) {
            const __bf16* ht = hp + (size_t)(t - 1) * Hz;
#pragma unroll 8
            for (int kk = 0; kk < Hz / 32; ++kk) {
                bf16x8 a  = *(const bf16x8*)(ht + kk * 32);
                bf16x8 w0v = *(const bf16x8*)(whp[0] + kk * 32);
                bf16x8 w1v = *(const bf16x8*)(whp[1] + kk * 32);
                ah0 = MFMA16(a, w0v, ah0);
                ah1 = MFMA16(a, w1v, ah1);
            }
        }
#pragma unroll
        for (int r = 0; r < 4; ++r) {
            int m = wave * 16 + lg * 4 + r;
            zbuf[m * 33 + l15]      = ax0[r] + ah0[r] + bv[0];
            zbuf[m * 33 + 16 + l15] = ax1[r] + ah1[r] + bv[1];
        }
        __syncthreads();
        {
            float zi = zbuf[gB0*33 + gJ0], zf = zbuf[gB0*33 + 8 + gJ0];
            float zo = zbuf[gB0*33 + 16 + gJ0], zg = zbuf[gB0*33 + 24 + gJ0];
            float cn = sigm(zf) * cs0 + sigm(zi) * tanhf(zg);
            float hn = sigm(zo) * tanhf(cn);
            cs0 = cn;
            y0[((size_t)gB0 * Tz + t) * Hz + j0 + gJ0] = (__bf16)hn;
        }
        {
            float zi = zbuf[gB1*33 + gJ1], zf = zbuf[gB1*33 + 8 + gJ1];
            float zo = zbuf[gB1*33 + 16 + gJ1], zg = zbuf[gB1*33 + 24 + gJ1];
            float cn = sigm(zf) * cs1 + sigm(zi) * tanhf(zg);
            float hn = sigm(zo) * tanhf(cn);
            cs1 = cn;
            y0[((size_t)gB1 * Tz + t) * Hz + j0 + gJ1] = (__bf16)hn;
        }
        grid.sync();
    }
}

// ---------------- layer 1: x = y0 bf16 (exact), h from d_out f32 (RNE cast) ----------------
__device__ __forceinline__ void layer1(
    const __bf16* __restrict__ y0, const __bf16* __restrict__ w1c,
    const float* __restrict__ b1, float* out, float* zbuf, cg::grid_group& grid)
{
    const int tid  = threadIdx.x;
    const int wave = tid >> 6, lane = tid & 63, l15 = lane & 15, lg = lane >> 4;
    const int j0   = blockIdx.x * NJ;

    const __bf16* wxp[2]; const __bf16* whp[2]; float bv[2];
#pragma unroll
    for (int tn = 0; tn < 2; ++tn) {
        int c = tn * 16 + l15, gate = c >> 3, j = c & 7;
        int row = gate * Hz + j0 + j;
        wxp[tn] = w1c + (size_t)row * 2048 + lg * 8;          // cols [0,1024): vs y0
        whp[tn] = w1c + (size_t)row * 2048 + 1024 + lg * 8;   // cols [1024,2048): vs h
        bv[tn]  = b1[row];
    }
    const int bA = wave * 16 + l15;
    const __bf16* xp = y0  + (size_t)bA * Tz * Hz + lg * 8;
    const float*  hp = out + (size_t)bA * Tz * Hz + lg * 8;

    const int idx0 = tid * 2, idx1 = idx0 + 1;
    const int gB0 = idx0 >> 3, gJ0 = idx0 & 7, gB1 = idx1 >> 3, gJ1 = idx1 & 7;
    float cs0 = 0.f, cs1 = 0.f;

    for (int t = 0; t < Tz; ++t) {
        f32x4 ax0 = {0,0,0,0}, ax1 = {0,0,0,0}, ah0 = {0,0,0,0}, ah1 = {0,0,0,0};

        const __bf16* xt = xp + (size_t)t * Hz;
#pragma unroll 8
        for (int kk = 0; kk < Hz / 32; ++kk) {
            bf16x8 a   = *(const bf16x8*)(xt + kk * 32);
            bf16x8 w0v = *(const bf16x8*)(wxp[0] + kk * 32);
            bf16x8 w1v = *(const bf16x8*)(wxp[1] + kk * 32);
            ax0 = MFMA16(a, w0v, ax0);
            ax1 = MFMA16(a, w1v, ax1);
        }
        if (t > 0) {
            const float* ht = hp + (size_t)(t - 1) * Hz;
#pragma unroll 4
            for (int kk = 0; kk < Hz / 32; ++kk) {
                f32x4 va = *(const f32x4*)(ht + kk * 32);
                f32x4 vb = *(const f32x4*)(ht + kk * 32 + 4);
                bf16x8 a;
#pragma unroll
                for (int e = 0; e < 4; ++e) { a[e] = (__bf16)va[e]; a[4 + e] = (__bf16)vb[e]; }
                bf16x8 w0v = *(const bf16x8*)(whp[0] + kk * 32);
                bf16x8 w1v = *(const bf16x8*)(whp[1] + kk * 32);
                ah0 = MFMA16(a, w0v, ah0);
                ah1 = MFMA16(a, w1v, ah1);
            }
        }
#pragma unroll
        for (int r = 0; r < 4; ++r) {
            int m = wave * 16 + lg * 4 + r;
            zbuf[m * 33 + l15]      = ax0[r] + ah0[r] + bv[0];
            zbuf[m * 33 + 16 + l15] = ax1[r] + ah1[r] + bv[1];
        }
        __syncthreads();
        {
            float zi = zbuf[gB0*33 + gJ0], zf = zbuf[gB0*33 + 8 + gJ0];
            float zo = zbuf[gB0*33 + 16 + gJ0], zg = zbuf[gB0*33 + 24 + gJ0];
            float cn = sigm(zf) * cs0 + sigm(zi) * tanhf(zg);
            float hn = sigm(zo) * tanhf(cn);
            cs0 = cn;
            out[((size_t)gB0 * Tz + t) * Hz + j0 + gJ0] = hn;
        }
        {
            float zi = zbuf[gB1*33 + gJ1], zf = zbuf[gB1*33 + 8 + gJ1];
            float zo = zbuf[gB1*33 + 16 + gJ1], zg = zbuf[gB1*33 + 24 + gJ1];
            float cn = sigm(zf) * cs1 + sigm(zi) * tanhf(zg);
            float hn = sigm(zo) * tanhf(cn);
            cs1 = cn;
            out[((size_t)gB1 * Tz + t) * Hz + j0 + gJ1] = hn;
        }
        grid.sync();
    }
}

extern "C" __global__ void __launch_bounds__(256, 1)
lstm2(const float* __restrict__ x,
      const float* __restrict__ b0,
      const float* __restrict__ b1,
      __bf16* ws,
      float* out)
{
    __shared__ float zbuf[64 * 33];
    cg::grid_group grid = cg::this_grid();

    const __bf16* w0xh = ws + OFF_W0XH;
    const __bf16* w0xl = ws + OFF_W0XL;
    const __bf16* w0h  = ws + OFF_W0H;
    const __bf16* w1c  = ws + OFF_W1;
    __bf16* y0         = ws + OFF_Y0;

    layer0(x, w0xh, w0xl, w0h, b0, y0, zbuf, grid);
    layer1(y0, w1c, b1, out, zbuf, grid);
}

extern "C" void kernel_launch(void* const* d_in, const int* in_sizes, int n_in,
                              void* d_out, int out_size, void* d_ws, size_t ws_size,
                              hipStream_t stream)
{
    const float* x  = (const float*)d_in[0];
    const float* W0 = (const float*)d_in[1];
    const float* b0 = (const float*)d_in[2];
    const float* W1 = (const float*)d_in[3];
    const float* b1 = (const float*)d_in[4];
    float* out = (float*)d_out;
    __bf16* ws = (__bf16*)d_ws;

    hipLaunchKernelGGL(prep_split, dim3(2048), dim3(256), 0, stream, W0, W1, ws);

    void* args[] = { (void*)&x, (void*)&b0, (void*)&b1, (void*)&ws, (void*)&out };
    hipLaunchCooperativeKernel(reinterpret_cast<void*>(lstm2),
                               dim3(NWG), dim3(256), args, 0, stream);
}

// Round 3
// 26957.208 us; speedup vs baseline: 1.6513x; 1.6513x over previous
//
#include <hip/hip_runtime.h>
#include <hip/hip_bf16.h>

typedef __bf16 bf16x8 __attribute__((ext_vector_type(8)));
typedef float  f32x4  __attribute__((ext_vector_type(4)));

#define MFMA16(a, b, c) __builtin_amdgcn_mfma_f32_16x16x32_bf16((a), (b), (c), 0, 0, 0)

static constexpr int Bz = 64, Tz = 512, Dz = 512, Hz = 1024;
static constexpr int NWG0 = 128;   // layer-0 WGs
static constexpr int NWGT = 256;   // total WGs (layer0 + layer1)
static constexpr int NJ   = 8;     // h-columns per WG

// ws layout, in bf16 elements
static constexpr size_t N_W0X = 4096ull * 512;
static constexpr size_t N_W0H = 4096ull * 1024;
static constexpr size_t N_W1  = 4096ull * 2048;
static constexpr size_t N_Y0  = 64ull * 512 * 1024;
static constexpr size_t OFF_W0XH = 0;
static constexpr size_t OFF_W0XL = OFF_W0XH + N_W0X;
static constexpr size_t OFF_W0H  = OFF_W0XL + N_W0X;
static constexpr size_t OFF_W1   = OFF_W0H  + N_W0H;
static constexpr size_t OFF_Y0   = OFF_W1   + N_W1;
static constexpr size_t OFF_BAR  = OFF_Y0   + N_Y0;   // byte offset = OFF_BAR*2, 128B-aligned

__device__ __forceinline__ float sigm(float x) { return 1.0f / (1.0f + __expf(-x)); }

// ---------------- prep: split/cast weights to bf16 in ws; reset barrier ----------------
extern "C" __global__ void prep_split(const float* __restrict__ W0,
                                      const float* __restrict__ W1,
                                      __bf16* __restrict__ ws)
{
    if (blockIdx.x == 0 && threadIdx.x == 0)
        *(unsigned*)((char*)ws + OFF_BAR * 2) = 0u;

    __bf16* w0xh = ws + OFF_W0XH;
    __bf16* w0xl = ws + OFF_W0XL;
    __bf16* w0h  = ws + OFF_W0H;
    __bf16* w1c  = ws + OFF_W1;
    const size_t ntot = N_W0X + N_W0H + N_W1;
    for (size_t idx = (size_t)blockIdx.x * blockDim.x + threadIdx.x;
         idx < ntot; idx += (size_t)gridDim.x * blockDim.x) {
        if (idx < N_W0X) {
            size_t r = idx >> 9, c = idx & 511;
            float w = W0[r * 1536 + c];
            __bf16 hi = (__bf16)w;
            w0xh[idx] = hi;
            w0xl[idx] = (__bf16)(w - (float)hi);
        } else if (idx < N_W0X + N_W0H) {
            size_t i = idx - N_W0X;
            size_t r = i >> 10, c = i & 1023;
            w0h[i] = (__bf16)W0[r * 1536 + 512 + c];
        } else {
            size_t i = idx - N_W0X - N_W0H;
            w1c[i] = (__bf16)W1[i];
        }
    }
}

// ---------------- custom grid barrier (monotonic counter, agent scope) ----------------
__device__ __forceinline__ void gridbar(unsigned* cnt, unsigned target)
{
    __syncthreads();   // drains this WG's stores (vmcnt) and syncs waves
    if (threadIdx.x == 0) {
        __hip_atomic_fetch_add(cnt, 1u, __ATOMIC_RELEASE, __HIP_MEMORY_SCOPE_AGENT);
        while (__hip_atomic_load(cnt, __ATOMIC_RELAXED, __HIP_MEMORY_SCOPE_AGENT) < target)
            __builtin_amdgcn_s_sleep(1);
    }
    __syncthreads();
    __builtin_amdgcn_fence(__ATOMIC_ACQUIRE, "agent");  // invalidate stale L1/L2 before h reads
}

// ---------------- layer 0 (WGs [0,128)): x f32 split on the fly, h bf16 (y0) ----------------
__device__ __forceinline__ void layer0(
    const float* __restrict__ x,
    const __bf16* __restrict__ w0xh, const __bf16* __restrict__ w0xl,
    const __bf16* __restrict__ w0h,  const float* __restrict__ b0,
    __bf16* y0, float* zbuf, unsigned* cnt)
{
    const int tid  = threadIdx.x;
    const int wave = tid >> 6, lane = tid & 63, l15 = lane & 15, lg = lane >> 4;
    const int j0   = blockIdx.x * NJ;

    const __bf16* wxh[2]; const __bf16* wxl[2]; const __bf16* whp[2]; float bv[2];
#pragma unroll
    for (int tn = 0; tn < 2; ++tn) {
        int c = tn * 16 + l15, gate = c >> 3, j = c & 7;
        int row = gate * Hz + j0 + j;
        wxh[tn] = w0xh + (size_t)row * Dz + lg * 8;
        wxl[tn] = w0xl + (size_t)row * Dz + lg * 8;
        whp[tn] = w0h  + (size_t)row * Hz + lg * 8;
        bv[tn]  = b0[row];
    }
    const int bA = wave * 16 + l15;
    const float*  xp = x  + (size_t)bA * Tz * Dz + lg * 8;
    const __bf16* hp = y0 + (size_t)bA * Tz * Hz + lg * 8;

    const int idx0 = tid * 2, idx1 = idx0 + 1;
    const int gB0 = idx0 >> 3, gJ0 = idx0 & 7, gB1 = idx1 >> 3, gJ1 = idx1 & 7;
    float cs0 = 0.f, cs1 = 0.f;

    for (int s = 0; s <= Tz; ++s) {
        if (s < Tz) {
            const int t = s;
            f32x4 ax0 = {0,0,0,0}, ax1 = {0,0,0,0}, ah0 = {0,0,0,0}, ah1 = {0,0,0,0};

            const float* xt = xp + (size_t)t * Dz;
#pragma unroll 4
            for (int kk = 0; kk < Dz / 32; ++kk) {
                f32x4 va = *(const f32x4*)(xt + kk * 32);
                f32x4 vb = *(const f32x4*)(xt + kk * 32 + 4);
                bf16x8 ahi, alo;
#pragma unroll
                for (int e = 0; e < 4; ++e) {
                    float v = va[e]; __bf16 h1 = (__bf16)v;
                    ahi[e] = h1; alo[e] = (__bf16)(v - (float)h1);
                    float w = vb[e]; __bf16 h2 = (__bf16)w;
                    ahi[4 + e] = h2; alo[4 + e] = (__bf16)(w - (float)h2);
                }
                bf16x8 wh0 = *(const bf16x8*)(wxh[0] + kk * 32);
                bf16x8 wl0 = *(const bf16x8*)(wxl[0] + kk * 32);
                bf16x8 wh1 = *(const bf16x8*)(wxh[1] + kk * 32);
                bf16x8 wl1 = *(const bf16x8*)(wxl[1] + kk * 32);
                ax0 = MFMA16(ahi, wh0, ax0); ax0 = MFMA16(alo, wh0, ax0); ax0 = MFMA16(ahi, wl0, ax0);
                ax1 = MFMA16(ahi, wh1, ax1); ax1 = MFMA16(alo, wh1, ax1); ax1 = MFMA16(ahi, wl1, ax1);
            }
            if (t > 0) {
                const __bf16* ht = hp + (size_t)(t - 1) * Hz;
#pragma unroll 8
                for (int kk = 0; kk < Hz / 32; ++kk) {
                    bf16x8 a   = *(const bf16x8*)(ht + kk * 32);
                    bf16x8 w0v = *(const bf16x8*)(whp[0] + kk * 32);
                    bf16x8 w1v = *(const bf16x8*)(whp[1] + kk * 32);
                    ah0 = MFMA16(a, w0v, ah0);
                    ah1 = MFMA16(a, w1v, ah1);
                }
            }
#pragma unroll
            for (int r = 0; r < 4; ++r) {
                int m = wave * 16 + lg * 4 + r;
                zbuf[m * 33 + l15]      = ax0[r] + ah0[r] + bv[0];
                zbuf[m * 33 + 16 + l15] = ax1[r] + ah1[r] + bv[1];
            }
            __syncthreads();
            {
                float zi = zbuf[gB0*33 + gJ0], zf = zbuf[gB0*33 + 8 + gJ0];
                float zo = zbuf[gB0*33 + 16 + gJ0], zg = zbuf[gB0*33 + 24 + gJ0];
                float cn = sigm(zf) * cs0 + sigm(zi) * tanhf(zg);
                float hn = sigm(zo) * tanhf(cn);
                cs0 = cn;
                y0[((size_t)gB0 * Tz + t) * Hz + j0 + gJ0] = (__bf16)hn;
            }
            {
                float zi = zbuf[gB1*33 + gJ1], zf = zbuf[gB1*33 + 8 + gJ1];
                float zo = zbuf[gB1*33 + 16 + gJ1], zg = zbuf[gB1*33 + 24 + gJ1];
                float cn = sigm(zf) * cs1 + sigm(zi) * tanhf(zg);
                float hn = sigm(zo) * tanhf(cn);
                cs1 = cn;
                y0[((size_t)gB1 * Tz + t) * Hz + j0 + gJ1] = (__bf16)hn;
            }
        }
        gridbar(cnt, (unsigned)(s + 1) * NWGT);
    }
}

// ---------------- layer 1 (WGs [128,256)): x = y0 bf16, h from d_out f32, one step behind ----------------
__device__ __forceinline__ void layer1(
    const __bf16* __restrict__ y0, const __bf16* __restrict__ w1c,
    const float* __restrict__ b1, float* out, float* zbuf, unsigned* cnt)
{
    const int tid  = threadIdx.x;
    const int wave = tid >> 6, lane = tid & 63, l15 = lane & 15, lg = lane >> 4;
    const int j0   = (blockIdx.x - NWG0) * NJ;

    const __bf16* wxp[2]; const __bf16* whp[2]; float bv[2];
#pragma unroll
    for (int tn = 0; tn < 2; ++tn) {
        int c = tn * 16 + l15, gate = c >> 3, j = c & 7;
        int row = gate * Hz + j0 + j;
        wxp[tn] = w1c + (size_t)row * 2048 + lg * 8;
        whp[tn] = w1c + (size_t)row * 2048 + 1024 + lg * 8;
        bv[tn]  = b1[row];
    }
    const int bA = wave * 16 + l15;
    const __bf16* xp = y0  + (size_t)bA * Tz * Hz + lg * 8;
    const float*  hp = out + (size_t)bA * Tz * Hz + lg * 8;

    const int idx0 = tid * 2, idx1 = idx0 + 1;
    const int gB0 = idx0 >> 3, gJ0 = idx0 & 7, gB1 = idx1 >> 3, gJ1 = idx1 & 7;
    float cs0 = 0.f, cs1 = 0.f;

    for (int s = 0; s <= Tz; ++s) {
        if (s > 0) {
            const int t = s - 1;
            f32x4 ax0 = {0,0,0,0}, ax1 = {0,0,0,0}, ah0 = {0,0,0,0}, ah1 = {0,0,0,0};

            const __bf16* xt = xp + (size_t)t * Hz;
#pragma unroll 8
            for (int kk = 0; kk < Hz / 32; ++kk) {
                bf16x8 a   = *(const bf16x8*)(xt + kk * 32);
                bf16x8 w0v = *(const bf16x8*)(wxp[0] + kk * 32);
                bf16x8 w1v = *(const bf16x8*)(wxp[1] + kk * 32);
                ax0 = MFMA16(a, w0v, ax0);
                ax1 = MFMA16(a, w1v, ax1);
            }
            if (t > 0) {
                const float* ht = hp + (size_t)(t - 1) * Hz;
#pragma unroll 4
                for (int kk = 0; kk < Hz / 32; ++kk) {
                    f32x4 va = *(const f32x4*)(ht + kk * 32);
                    f32x4 vb = *(const f32x4*)(ht + kk * 32 + 4);
                    bf16x8 a;
#pragma unroll
                    for (int e = 0; e < 4; ++e) { a[e] = (__bf16)va[e]; a[4 + e] = (__bf16)vb[e]; }
                    bf16x8 w0v = *(const bf16x8*)(whp[0] + kk * 32);
                    bf16x8 w1v = *(const bf16x8*)(whp[1] + kk * 32);
                    ah0 = MFMA16(a, w0v, ah0);
                    ah1 = MFMA16(a, w1v, ah1);
                }
            }
#pragma unroll
            for (int r = 0; r < 4; ++r) {
                int m = wave * 16 + lg * 4 + r;
                zbuf[m * 33 + l15]      = ax0[r] + ah0[r] + bv[0];
                zbuf[m * 33 + 16 + l15] = ax1[r] + ah1[r] + bv[1];
            }
            __syncthreads();
            {
                float zi = zbuf[gB0*33 + gJ0], zf = zbuf[gB0*33 + 8 + gJ0];
                float zo = zbuf[gB0*33 + 16 + gJ0], zg = zbuf[gB0*33 + 24 + gJ0];
                float cn = sigm(zf) * cs0 + sigm(zi) * tanhf(zg);
                float hn = sigm(zo) * tanhf(cn);
                cs0 = cn;
                out[((size_t)gB0 * Tz + t) * Hz + j0 + gJ0] = hn;
            }
            {
                float zi = zbuf[gB1*33 + gJ1], zf = zbuf[gB1*33 + 8 + gJ1];
                float zo = zbuf[gB1*33 + 16 + gJ1], zg = zbuf[gB1*33 + 24 + gJ1];
                float cn = sigm(zf) * cs1 + sigm(zi) * tanhf(zg);
                float hn = sigm(zo) * tanhf(cn);
                cs1 = cn;
                out[((size_t)gB1 * Tz + t) * Hz + j0 + gJ1] = hn;
            }
        }
        gridbar(cnt, (unsigned)(s + 1) * NWGT);
    }
}

extern "C" __global__ void __launch_bounds__(256, 1)
lstm2(const float* __restrict__ x,
      const float* __restrict__ b0,
      const float* __restrict__ b1,
      __bf16* ws,
      float* out)
{
    __shared__ float zbuf[64 * 33];
    unsigned* cnt = (unsigned*)((char*)ws + OFF_BAR * 2);

    if (blockIdx.x < NWG0)
        layer0(x, ws + OFF_W0XH, ws + OFF_W0XL, ws + OFF_W0H, b0, ws + OFF_Y0, zbuf, cnt);
    else
        layer1(ws + OFF_Y0, ws + OFF_W1, b1, out, zbuf, cnt);
}

extern "C" void kernel_launch(void* const* d_in, const int* in_sizes, int n_in,
                              void* d_out, int out_size, void* d_ws, size_t ws_size,
                              hipStream_t stream)
{
    const float* x  = (const float*)d_in[0];
    const float* W0 = (const float*)d_in[1];
    const float* b0 = (const float*)d_in[2];
    const float* W1 = (const float*)d_in[3];
    const float* b1 = (const float*)d_in[4];
    float* out = (float*)d_out;
    __bf16* ws = (__bf16*)d_ws;

    hipLaunchKernelGGL(prep_split, dim3(2048), dim3(256), 0, stream, W0, W1, ws);

    void* args[] = { (void*)&x, (void*)&b0, (void*)&b1, (void*)&ws, (void*)&out };
    hipLaunchCooperativeKernel(reinterpret_cast<void*>(lstm2),
                               dim3(NWGT), dim3(256), args, 0, stream);
}

// Round 4
// 19861.038 us; speedup vs baseline: 2.2413x; 1.3573x over previous
//
#include <hip/hip_runtime.h>
#include <hip/hip_bf16.h>

typedef __bf16 bf16x8 __attribute__((ext_vector_type(8)));
typedef float  f32x4  __attribute__((ext_vector_type(4)));

#define MFMA16(a, b, c) __builtin_amdgcn_mfma_f32_16x16x32_bf16((a), (b), (c), 0, 0, 0)

static constexpr int Bz = 64, Tz = 512, Dz = 512, Hz = 1024;
static constexpr int NWG0 = 128;   // layer-0 WGs
static constexpr int NWGT = 256;   // total WGs
static constexpr int NJ   = 8;     // h-columns per WG

// ws layout, in bf16 elements
static constexpr size_t N_W0X = 4096ull * 512;
static constexpr size_t N_W0H = 4096ull * 1024;
static constexpr size_t N_W1  = 4096ull * 2048;
static constexpr size_t N_Y0  = 64ull * 512 * 1024;
static constexpr size_t OFF_W0XH = 0;
static constexpr size_t OFF_W0XL = OFF_W0XH + N_W0X;
static constexpr size_t OFF_W0H  = OFF_W0XL + N_W0X;
static constexpr size_t OFF_W1   = OFF_W0H  + N_W0H;
static constexpr size_t OFF_Y0   = OFF_W1   + N_W1;
static constexpr size_t OFF_BAR  = OFF_Y0   + N_Y0;   // byte offset = OFF_BAR*2

__device__ __forceinline__ float sigm(float x) { return 1.0f / (1.0f + __expf(-x)); }

// ---------------- prep: split/cast weights to bf16 in ws; reset barrier ----------------
extern "C" __global__ void prep_split(const float* __restrict__ W0,
                                      const float* __restrict__ W1,
                                      __bf16* __restrict__ ws)
{
    if (blockIdx.x == 0 && threadIdx.x == 0)
        *(unsigned*)((char*)ws + OFF_BAR * 2) = 0u;

    __bf16* w0xh = ws + OFF_W0XH;
    __bf16* w0xl = ws + OFF_W0XL;
    __bf16* w0h  = ws + OFF_W0H;
    __bf16* w1c  = ws + OFF_W1;
    const size_t ntot = N_W0X + N_W0H + N_W1;
    for (size_t idx = (size_t)blockIdx.x * blockDim.x + threadIdx.x;
         idx < ntot; idx += (size_t)gridDim.x * blockDim.x) {
        if (idx < N_W0X) {
            size_t r = idx >> 9, c = idx & 511;
            float w = W0[r * 1536 + c];
            __bf16 hi = (__bf16)w;
            w0xh[idx] = hi;
            w0xl[idx] = (__bf16)(w - (float)hi);
        } else if (idx < N_W0X + N_W0H) {
            size_t i = idx - N_W0X;
            size_t r = i >> 10, c = i & 1023;
            w0h[i] = (__bf16)W0[r * 1536 + 512 + c];
        } else {
            size_t i = idx - N_W0X - N_W0H;
            w1c[i] = (__bf16)W1[i];
        }
    }
}

// ---------------- split barrier: release-arrive, relaxed-spin wait, NO L2 invalidate ----
// Correctness: all cross-WG data (y0[t], out[t]) is read at monotonically fresh
// addresses (t-stride 2KB/4KB -> no cache-line reuse across steps), so no stale
// L1/L2 copies can exist. Release side: __syncthreads drains each wave's stores
// to L2; the RELEASE atomic emits buffer_wbl2 + waitcnt before the add is
// visible -> data at LLC before peers can observe the count.
__device__ __forceinline__ void bar_arrive(unsigned* cnt)
{
    __syncthreads();
    if (threadIdx.x == 0)
        __hip_atomic_fetch_add(cnt, 1u, __ATOMIC_RELEASE, __HIP_MEMORY_SCOPE_AGENT);
}

__device__ __forceinline__ void bar_wait(unsigned* cnt, unsigned target)
{
    if (threadIdx.x == 0) {
        while (__hip_atomic_load(cnt, __ATOMIC_RELAXED, __HIP_MEMORY_SCOPE_AGENT) < target)
            __builtin_amdgcn_s_sleep(1);
    }
    __syncthreads();
    asm volatile("" ::: "memory");   // compiler fence only; no cache invalidate
}

// x-part GEMM for one step (hi/lo split on the fly)
__device__ __forceinline__ void zx_compute(const float* __restrict__ xt,
    const __bf16* wxh0, const __bf16* wxl0,
    const __bf16* wxh1, const __bf16* wxl1,
    f32x4& zx0, f32x4& zx1)
{
    f32x4 a0 = {0,0,0,0}, a1 = {0,0,0,0};
#pragma unroll 4
    for (int kk = 0; kk < Dz / 32; ++kk) {
        f32x4 va = *(const f32x4*)(xt + kk * 32);
        f32x4 vb = *(const f32x4*)(xt + kk * 32 + 4);
        bf16x8 ahi, alo;
#pragma unroll
        for (int e = 0; e < 4; ++e) {
            float v = va[e]; __bf16 h1 = (__bf16)v;
            ahi[e] = h1; alo[e] = (__bf16)(v - (float)h1);
            float w = vb[e]; __bf16 h2 = (__bf16)w;
            ahi[4 + e] = h2; alo[4 + e] = (__bf16)(w - (float)h2);
        }
        bf16x8 wh0 = *(const bf16x8*)(wxh0 + kk * 32);
        bf16x8 wl0 = *(const bf16x8*)(wxl0 + kk * 32);
        bf16x8 wh1 = *(const bf16x8*)(wxh1 + kk * 32);
        bf16x8 wl1 = *(const bf16x8*)(wxl1 + kk * 32);
        a0 = MFMA16(ahi, wh0, a0); a0 = MFMA16(alo, wh0, a0); a0 = MFMA16(ahi, wl0, a0);
        a1 = MFMA16(ahi, wh1, a1); a1 = MFMA16(alo, wh1, a1); a1 = MFMA16(ahi, wl1, a1);
    }
    zx0 = a0; zx1 = a1;
}

// ---------------- layer 0 (WGs [0,128)) ----------------
__device__ __forceinline__ void layer0(
    const float* __restrict__ x,
    const __bf16* __restrict__ w0xh, const __bf16* __restrict__ w0xl,
    const __bf16* __restrict__ w0h,  const float* __restrict__ b0,
    __bf16* y0, float* zbuf, unsigned* cnt)
{
    const int tid  = threadIdx.x;
    const int wave = tid >> 6, lane = tid & 63, l15 = lane & 15, lg = lane >> 4;
    const int j0   = blockIdx.x * NJ;

    const __bf16* wxh[2]; const __bf16* wxl[2]; const __bf16* whp[2]; float bv[2];
#pragma unroll
    for (int tn = 0; tn < 2; ++tn) {
        int c = tn * 16 + l15, gate = c >> 3, j = c & 7;
        int row = gate * Hz + j0 + j;
        wxh[tn] = w0xh + (size_t)row * Dz + lg * 8;
        wxl[tn] = w0xl + (size_t)row * Dz + lg * 8;
        whp[tn] = w0h  + (size_t)row * Hz + lg * 8;
        bv[tn]  = b0[row];
    }
    const int bA = wave * 16 + l15;
    const float*  xp = x  + (size_t)bA * Tz * Dz + lg * 8;
    const __bf16* hp = y0 + (size_t)bA * Tz * Hz + lg * 8;

    const int idx0 = tid * 2, idx1 = idx0 + 1;
    const int gB0 = idx0 >> 3, gJ0 = idx0 & 7, gB1 = idx1 >> 3, gJ1 = idx1 & 7;
    float cs0 = 0.f, cs1 = 0.f;

    f32x4 zx0, zx1;
    zx_compute(xp, wxh[0], wxl[0], wxh[1], wxl[1], zx0, zx1);   // t = 0

    for (int s = 0; s < Tz; ++s) {
        f32x4 ah0 = {0,0,0,0}, ah1 = {0,0,0,0};
        if (s > 0) {
            bar_wait(cnt, (unsigned)s * NWGT);                   // y0[s-1] visible
            const __bf16* ht = hp + (size_t)(s - 1) * Hz;
#pragma unroll 8
            for (int kk = 0; kk < Hz / 32; ++kk) {
                bf16x8 a   = *(const bf16x8*)(ht + kk * 32);
                bf16x8 w0v = *(const bf16x8*)(whp[0] + kk * 32);
                bf16x8 w1v = *(const bf16x8*)(whp[1] + kk * 32);
                ah0 = MFMA16(a, w0v, ah0);
                ah1 = MFMA16(a, w1v, ah1);
            }
        }
#pragma unroll
        for (int r = 0; r < 4; ++r) {
            int m = wave * 16 + lg * 4 + r;
            zbuf[m * 33 + l15]      = zx0[r] + ah0[r] + bv[0];
            zbuf[m * 33 + 16 + l15] = zx1[r] + ah1[r] + bv[1];
        }
        __syncthreads();
        {
            float zi = zbuf[gB0*33 + gJ0], zf = zbuf[gB0*33 + 8 + gJ0];
            float zo = zbuf[gB0*33 + 16 + gJ0], zg = zbuf[gB0*33 + 24 + gJ0];
            float cn = sigm(zf) * cs0 + sigm(zi) * tanhf(zg);
            float hn = sigm(zo) * tanhf(cn);
            cs0 = cn;
            y0[((size_t)gB0 * Tz + s) * Hz + j0 + gJ0] = (__bf16)hn;
        }
        {
            float zi = zbuf[gB1*33 + gJ1], zf = zbuf[gB1*33 + 8 + gJ1];
            float zo = zbuf[gB1*33 + 16 + gJ1], zg = zbuf[gB1*33 + 24 + gJ1];
            float cn = sigm(zf) * cs1 + sigm(zi) * tanhf(zg);
            float hn = sigm(zo) * tanhf(cn);
            cs1 = cn;
            y0[((size_t)gB1 * Tz + s) * Hz + j0 + gJ1] = (__bf16)hn;
        }
        bar_arrive(cnt);                                         // publish y0[s]
        if (s < Tz - 1)                                          // shadow: x-part of t=s+1
            zx_compute(xp + (size_t)(s + 1) * Dz, wxh[0], wxl[0], wxh[1], wxl[1], zx0, zx1);
    }
}

// ---------------- layer 1 (WGs [128,256)), one step behind ----------------
__device__ __forceinline__ void layer1(
    const __bf16* __restrict__ y0, const __bf16* __restrict__ w1c,
    const float* __restrict__ b1, float* out, float* zbuf, unsigned* cnt)
{
    const int tid  = threadIdx.x;
    const int wave = tid >> 6, lane = tid & 63, l15 = lane & 15, lg = lane >> 4;
    const int j0   = (blockIdx.x - NWG0) * NJ;

    const __bf16* wxp[2]; const __bf16* whp[2]; float bv[2];
#pragma unroll
    for (int tn = 0; tn < 2; ++tn) {
        int c = tn * 16 + l15, gate = c >> 3, j = c & 7;
        int row = gate * Hz + j0 + j;
        wxp[tn] = w1c + (size_t)row * 2048 + lg * 8;
        whp[tn] = w1c + (size_t)row * 2048 + 1024 + lg * 8;
        bv[tn]  = b1[row];
    }
    const int bA = wave * 16 + l15;
    const __bf16* xp = y0  + (size_t)bA * Tz * Hz + lg * 8;
    const float*  hp = out + (size_t)bA * Tz * Hz + lg * 8;

    const int idx0 = tid * 2, idx1 = idx0 + 1;
    const int gB0 = idx0 >> 3, gJ0 = idx0 & 7, gB1 = idx1 >> 3, gJ1 = idx1 & 7;
    float cs0 = 0.f, cs1 = 0.f;

    bar_arrive(cnt);   // iteration-0 arrival (no compute yet)

    for (int s = 1; s <= Tz; ++s) {
        bar_wait(cnt, (unsigned)s * NWGT);      // y0[s-1] and out[s-2] visible
        const int t = s - 1;
        f32x4 ax0 = {bv[0], bv[0], bv[0], bv[0]};
        f32x4 ax1 = {bv[1], bv[1], bv[1], bv[1]};

        const __bf16* xt = xp + (size_t)t * Hz;
#pragma unroll 8
        for (int kk = 0; kk < Hz / 32; ++kk) {
            bf16x8 a   = *(const bf16x8*)(xt + kk * 32);
            bf16x8 w0v = *(const bf16x8*)(wxp[0] + kk * 32);
            bf16x8 w1v = *(const bf16x8*)(wxp[1] + kk * 32);
            ax0 = MFMA16(a, w0v, ax0);
            ax1 = MFMA16(a, w1v, ax1);
        }
        if (t > 0) {
            const float* ht = hp + (size_t)(t - 1) * Hz;
#pragma unroll 4
            for (int kk = 0; kk < Hz / 32; ++kk) {
                f32x4 va = *(const f32x4*)(ht + kk * 32);
                f32x4 vb = *(const f32x4*)(ht + kk * 32 + 4);
                bf16x8 a;
#pragma unroll
                for (int e = 0; e < 4; ++e) { a[e] = (__bf16)va[e]; a[4 + e] = (__bf16)vb[e]; }
                bf16x8 w0v = *(const bf16x8*)(whp[0] + kk * 32);
                bf16x8 w1v = *(const bf16x8*)(whp[1] + kk * 32);
                ax0 = MFMA16(a, w0v, ax0);
                ax1 = MFMA16(a, w1v, ax1);
            }
        }
#pragma unroll
        for (int r = 0; r < 4; ++r) {
            int m = wave * 16 + lg * 4 + r;
            zbuf[m * 33 + l15]      = ax0[r];
            zbuf[m * 33 + 16 + l15] = ax1[r];
        }
        __syncthreads();
        {
            float zi = zbuf[gB0*33 + gJ0], zf = zbuf[gB0*33 + 8 + gJ0];
            float zo = zbuf[gB0*33 + 16 + gJ0], zg = zbuf[gB0*33 + 24 + gJ0];
            float cn = sigm(zf) * cs0 + sigm(zi) * tanhf(zg);
            float hn = sigm(zo) * tanhf(cn);
            cs0 = cn;
            out[((size_t)gB0 * Tz + t) * Hz + j0 + gJ0] = hn;
        }
        {
            float zi = zbuf[gB1*33 + gJ1], zf = zbuf[gB1*33 + 8 + gJ1];
            float zo = zbuf[gB1*33 + 16 + gJ1], zg = zbuf[gB1*33 + 24 + gJ1];
            float cn = sigm(zf) * cs1 + sigm(zi) * tanhf(zg);
            float hn = sigm(zo) * tanhf(cn);
            cs1 = cn;
            out[((size_t)gB1 * Tz + t) * Hz + j0 + gJ1] = hn;
        }
        if (s < Tz) bar_arrive(cnt);            // publish out[t]
    }
}

extern "C" __global__ void __launch_bounds__(256, 1)
lstm2(const float* __restrict__ x,
      const float* __restrict__ b0,
      const float* __restrict__ b1,
      __bf16* ws,
      float* out)
{
    __shared__ float zbuf[64 * 33];
    unsigned* cnt = (unsigned*)((char*)ws + OFF_BAR * 2);

    if (blockIdx.x < NWG0)
        layer0(x, ws + OFF_W0XH, ws + OFF_W0XL, ws + OFF_W0H, b0, ws + OFF_Y0, zbuf, cnt);
    else
        layer1(ws + OFF_Y0, ws + OFF_W1, b1, out, zbuf, cnt);
}

extern "C" void kernel_launch(void* const* d_in, const int* in_sizes, int n_in,
                              void* d_out, int out_size, void* d_ws, size_t ws_size,
                              hipStream_t stream)
{
    const float* x  = (const float*)d_in[0];
    const float* W0 = (const float*)d_in[1];
    const float* b0 = (const float*)d_in[2];
    const float* W1 = (const float*)d_in[3];
    const float* b1 = (const float*)d_in[4];
    float* out = (float*)d_out;
    __bf16* ws = (__bf16*)d_ws;

    hipLaunchKernelGGL(prep_split, dim3(2048), dim3(256), 0, stream, W0, W1, ws);

    void* args[] = { (void*)&x, (void*)&b0, (void*)&b1, (void*)&ws, (void*)&out };
    hipLaunchCooperativeKernel(reinterpret_cast<void*>(lstm2),
                               dim3(NWGT), dim3(256), args, 0, stream);
}

// Round 5
// 12637.957 us; speedup vs baseline: 3.5223x; 1.5715x over previous
//
#include <hip/hip_runtime.h>
#include <hip/hip_bf16.h>

typedef __bf16 bf16x8 __attribute__((ext_vector_type(8)));
typedef float  f32x4  __attribute__((ext_vector_type(4)));

#define MFMA16(a, b, c) __builtin_amdgcn_mfma_f32_16x16x32_bf16((a), (b), (c), 0, 0, 0)

static constexpr int Bz = 64, Tz = 512, Dz = 512, Hz = 1024;
static constexpr int NWG0 = 128;   // layer-0 WGs
static constexpr int NWGT = 256;   // total WGs
static constexpr int NJ   = 8;     // h-columns per WG

// LDS tile pitches (bf16 elements), +8 pad (16B) to stagger banks: 2064B%128B=16B -> 2-way only
static constexpr int PXL = 512 + 8;
static constexpr int PHL = 1024 + 8;
static constexpr int ZBUF_BYTES = 64 * 33 * 4;                      // 8448, 16B-aligned
static constexpr size_t LDS_BYTES = ZBUF_BYTES + (size_t)(2 * 32 * PXL + 32 * PHL) * 2;  // 141056

// ws layout, in bf16 elements
static constexpr size_t N_W0X = 4096ull * 512;
static constexpr size_t N_W0H = 4096ull * 1024;
static constexpr size_t N_W1  = 4096ull * 2048;
static constexpr size_t N_Y0  = 64ull * 512 * 1024;
static constexpr size_t OFF_W0XH = 0;
static constexpr size_t OFF_W0XL = OFF_W0XH + N_W0X;
static constexpr size_t OFF_W0H  = OFF_W0XL + N_W0X;
static constexpr size_t OFF_W1   = OFF_W0H  + N_W0H;
static constexpr size_t OFF_Y0   = OFF_W1   + N_W1;
static constexpr size_t OFF_BAR  = OFF_Y0   + N_Y0;   // byte offset = OFF_BAR*2

__device__ __forceinline__ float sigm(float x) { return 1.0f / (1.0f + __expf(-x)); }

// ---------------- prep: split/cast weights to bf16 in ws; reset barriers ----------------
extern "C" __global__ void prep_split(const float* __restrict__ W0,
                                      const float* __restrict__ W1,
                                      __bf16* __restrict__ ws)
{
    if (blockIdx.x == 0 && threadIdx.x == 0) {
        *(unsigned*)((char*)ws + OFF_BAR * 2) = 0u;          // cnt0 (layer-0 arrivals)
        *(unsigned*)((char*)ws + OFF_BAR * 2 + 128) = 0u;    // cnt1 (layer-1 arrivals)
    }
    __bf16* w0xh = ws + OFF_W0XH;
    __bf16* w0xl = ws + OFF_W0XL;
    __bf16* w0h  = ws + OFF_W0H;
    __bf16* w1c  = ws + OFF_W1;
    const size_t ntot = N_W0X + N_W0H + N_W1;
    for (size_t idx = (size_t)blockIdx.x * blockDim.x + threadIdx.x;
         idx < ntot; idx += (size_t)gridDim.x * blockDim.x) {
        if (idx < N_W0X) {
            size_t r = idx >> 9, c = idx & 511;
            float w = W0[r * 1536 + c];
            __bf16 hi = (__bf16)w;
            w0xh[idx] = hi;
            w0xl[idx] = (__bf16)(w - (float)hi);
        } else if (idx < N_W0X + N_W0H) {
            size_t i = idx - N_W0X;
            size_t r = i >> 10, c = i & 1023;
            w0h[i] = (__bf16)W0[r * 1536 + 512 + c];
        } else {
            size_t i = idx - N_W0X - N_W0H;
            w1c[i] = (__bf16)W1[i];
        }
    }
}

// ---------------- split barrier: release-arrive, relaxed-spin wait, NO L2 invalidate ----
// All cross-WG data is read at monotonically fresh addresses (t-stride 2KB/4KB), so no
// stale copies can exist in a reader's caches. Release on the arrive makes the writer's
// h-stores visible at the coherence point before the count is observable.
__device__ __forceinline__ void bar_arrive(unsigned* cnt)
{
    __syncthreads();
    if (threadIdx.x == 0)
        __hip_atomic_fetch_add(cnt, 1u, __ATOMIC_RELEASE, __HIP_MEMORY_SCOPE_AGENT);
}

__device__ __forceinline__ void wait_ge(unsigned* cnt, unsigned target)
{
    while (__hip_atomic_load(cnt, __ATOMIC_RELAXED, __HIP_MEMORY_SCOPE_AGENT) < target)
        __builtin_amdgcn_s_sleep(1);
}

// x-part GEMM for one step (hi/lo split on the fly); weights from LDS
__device__ __forceinline__ void zx_compute(const float* __restrict__ xt,
    const __bf16* wxh0, const __bf16* wxl0,
    const __bf16* wxh1, const __bf16* wxl1,
    f32x4& zx0, f32x4& zx1)
{
    f32x4 a0 = {0,0,0,0}, a1 = {0,0,0,0};
#pragma unroll 4
    for (int kk = 0; kk < Dz / 32; ++kk) {
        f32x4 va = *(const f32x4*)(xt + kk * 32);
        f32x4 vb = *(const f32x4*)(xt + kk * 32 + 4);
        bf16x8 ahi, alo;
#pragma unroll
        for (int e = 0; e < 4; ++e) {
            float v = va[e]; __bf16 h1 = (__bf16)v;
            ahi[e] = h1; alo[e] = (__bf16)(v - (float)h1);
            float w = vb[e]; __bf16 h2 = (__bf16)w;
            ahi[4 + e] = h2; alo[4 + e] = (__bf16)(w - (float)h2);
        }
        bf16x8 wh0 = *(const bf16x8*)(wxh0 + kk * 32);
        bf16x8 wl0 = *(const bf16x8*)(wxl0 + kk * 32);
        bf16x8 wh1 = *(const bf16x8*)(wxh1 + kk * 32);
        bf16x8 wl1 = *(const bf16x8*)(wxl1 + kk * 32);
        a0 = MFMA16(ahi, wh0, a0); a0 = MFMA16(alo, wh0, a0); a0 = MFMA16(ahi, wl0, a0);
        a1 = MFMA16(ahi, wh1, a1); a1 = MFMA16(alo, wh1, a1); a1 = MFMA16(ahi, wl1, a1);
    }
    zx0 = a0; zx1 = a1;
}

// ---------------- layer 0 (WGs [0,128)) ----------------
__device__ __forceinline__ void layer0(
    const float* __restrict__ x,
    const __bf16* __restrict__ w0xh, const __bf16* __restrict__ w0xl,
    const __bf16* __restrict__ w0h,  const float* __restrict__ b0,
    __bf16* y0, float* zbuf, __bf16* wtile, unsigned* cnt0)
{
    const int tid  = threadIdx.x;
    const int wave = tid >> 6, lane = tid & 63, l15 = lane & 15, lg = lane >> 4;
    const int j0   = blockIdx.x * NJ;

    // ---- stage this WG's weight slice into LDS (once) ----
    __bf16* sWXH = wtile;
    __bf16* sWXL = wtile + 32 * PXL;
    __bf16* sWH  = wtile + 64 * PXL;
    for (int idx = tid; idx < 32 * (Dz / 8); idx += 256) {       // 2048 iters
        int r = idx >> 6, kc = (idx & 63) * 8;
        size_t grow = (size_t)((r >> 3) * Hz + j0 + (r & 7));
        *(bf16x8*)(sWXH + r * PXL + kc) = *(const bf16x8*)(w0xh + grow * Dz + kc);
        *(bf16x8*)(sWXL + r * PXL + kc) = *(const bf16x8*)(w0xl + grow * Dz + kc);
    }
    for (int idx = tid; idx < 32 * (Hz / 8); idx += 256) {       // 4096 iters
        int r = idx >> 7, kc = (idx & 127) * 8;
        size_t grow = (size_t)((r >> 3) * Hz + j0 + (r & 7));
        *(bf16x8*)(sWH + r * PHL + kc) = *(const bf16x8*)(w0h + grow * Hz + kc);
    }
    __syncthreads();

    const __bf16* wxh[2]; const __bf16* wxl[2]; const __bf16* whp[2]; float bv[2];
#pragma unroll
    for (int tn = 0; tn < 2; ++tn) {
        int c = tn * 16 + l15;
        wxh[tn] = sWXH + c * PXL + lg * 8;
        wxl[tn] = sWXL + c * PXL + lg * 8;
        whp[tn] = sWH  + c * PHL + lg * 8;
        bv[tn]  = b0[(c >> 3) * Hz + j0 + (c & 7)];
    }
    const int bA = wave * 16 + l15;
    const float*  xp = x  + (size_t)bA * Tz * Dz + lg * 8;
    const __bf16* hp = y0 + (size_t)bA * Tz * Hz + lg * 8;

    const int idx0 = tid * 2, idx1 = idx0 + 1;
    const int gB0 = idx0 >> 3, gJ0 = idx0 & 7, gB1 = idx1 >> 3, gJ1 = idx1 & 7;
    float cs0 = 0.f, cs1 = 0.f;

    f32x4 zx0, zx1;
    zx_compute(xp, wxh[0], wxl[0], wxh[1], wxl[1], zx0, zx1);   // t = 0

    for (int s = 0; s < Tz; ++s) {
        f32x4 ah0 = {0,0,0,0}, ah1 = {0,0,0,0};
        if (s > 0) {
            if (tid == 0) wait_ge(cnt0, (unsigned)s * NWG0);     // y0[s-1] visible
            __syncthreads();
            asm volatile("" ::: "memory");
            const __bf16* ht = hp + (size_t)(s - 1) * Hz;
#pragma unroll 8
            for (int kk = 0; kk < Hz / 32; ++kk) {
                bf16x8 a   = *(const bf16x8*)(ht + kk * 32);
                bf16x8 w0v = *(const bf16x8*)(whp[0] + kk * 32);
                bf16x8 w1v = *(const bf16x8*)(whp[1] + kk * 32);
                ah0 = MFMA16(a, w0v, ah0);
                ah1 = MFMA16(a, w1v, ah1);
            }
        }
#pragma unroll
        for (int r = 0; r < 4; ++r) {
            int m = wave * 16 + lg * 4 + r;
            zbuf[m * 33 + l15]      = zx0[r] + ah0[r] + bv[0];
            zbuf[m * 33 + 16 + l15] = zx1[r] + ah1[r] + bv[1];
        }
        __syncthreads();
        {
            float zi = zbuf[gB0*33 + gJ0], zf = zbuf[gB0*33 + 8 + gJ0];
            float zo = zbuf[gB0*33 + 16 + gJ0], zg = zbuf[gB0*33 + 24 + gJ0];
            float cn = sigm(zf) * cs0 + sigm(zi) * tanhf(zg);
            float hn = sigm(zo) * tanhf(cn);
            cs0 = cn;
            y0[((size_t)gB0 * Tz + s) * Hz + j0 + gJ0] = (__bf16)hn;
        }
        {
            float zi = zbuf[gB1*33 + gJ1], zf = zbuf[gB1*33 + 8 + gJ1];
            float zo = zbuf[gB1*33 + 16 + gJ1], zg = zbuf[gB1*33 + 24 + gJ1];
            float cn = sigm(zf) * cs1 + sigm(zi) * tanhf(zg);
            float hn = sigm(zo) * tanhf(cn);
            cs1 = cn;
            y0[((size_t)gB1 * Tz + s) * Hz + j0 + gJ1] = (__bf16)hn;
        }
        bar_arrive(cnt0);                                        // publish y0[s]
        if (s < Tz - 1)                                          // shadow: x-part of t=s+1
            zx_compute(xp + (size_t)(s + 1) * Dz, wxh[0], wxl[0], wxh[1], wxl[1], zx0, zx1);
    }
}

// ---------------- layer 1 (WGs [128,256)), trails layer 0 ----------------
__device__ __forceinline__ void layer1(
    const __bf16* __restrict__ y0, const __bf16* __restrict__ w1c,
    const float* __restrict__ b1, float* out, float* zbuf, __bf16* wtile,
    unsigned* cnt0, unsigned* cnt1)
{
    const int tid  = threadIdx.x;
    const int wave = tid >> 6, lane = tid & 63, l15 = lane & 15, lg = lane >> 4;
    const int j0   = (blockIdx.x - NWG0) * NJ;

    // ---- stage this WG's weight slice into LDS (once) ----
    __bf16* sWX = wtile;
    __bf16* sWH = wtile + 32 * PHL;
    for (int idx = tid; idx < 32 * (Hz / 8); idx += 256) {
        int r = idx >> 7, kc = (idx & 127) * 8;
        size_t grow = (size_t)((r >> 3) * Hz + j0 + (r & 7));
        const __bf16* srow = w1c + grow * 2048;
        *(bf16x8*)(sWX + r * PHL + kc) = *(const bf16x8*)(srow + kc);
        *(bf16x8*)(sWH + r * PHL + kc) = *(const bf16x8*)(srow + 1024 + kc);
    }
    __syncthreads();

    const __bf16* wxp[2]; const __bf16* whp[2]; float bv[2];
#pragma unroll
    for (int tn = 0; tn < 2; ++tn) {
        int c = tn * 16 + l15;
        wxp[tn] = sWX + c * PHL + lg * 8;
        whp[tn] = sWH + c * PHL + lg * 8;
        bv[tn]  = b1[(c >> 3) * Hz + j0 + (c & 7)];
    }
    const int bA = wave * 16 + l15;
    const __bf16* xp = y0  + (size_t)bA * Tz * Hz + lg * 8;
    const float*  hp = out + (size_t)bA * Tz * Hz + lg * 8;

    const int idx0 = tid * 2, idx1 = idx0 + 1;
    const int gB0 = idx0 >> 3, gJ0 = idx0 & 7, gB1 = idx1 >> 3, gJ1 = idx1 & 7;
    float cs0 = 0.f, cs1 = 0.f;

    for (int s = 1; s <= Tz; ++s) {
        if (tid == 0) {
            wait_ge(cnt0, (unsigned)s * NWG0);                   // y0[s-1] ready
            if (s >= 2) wait_ge(cnt1, (unsigned)(s - 1) * NWG0); // out[s-2] ready
        }
        __syncthreads();
        asm volatile("" ::: "memory");

        const int t = s - 1;
        f32x4 ax0 = {bv[0], bv[0], bv[0], bv[0]};
        f32x4 ax1 = {bv[1], bv[1], bv[1], bv[1]};

        const __bf16* xt = xp + (size_t)t * Hz;
#pragma unroll 8
        for (int kk = 0; kk < Hz / 32; ++kk) {
            bf16x8 a   = *(const bf16x8*)(xt + kk * 32);
            bf16x8 w0v = *(const bf16x8*)(wxp[0] + kk * 32);
            bf16x8 w1v = *(const bf16x8*)(wxp[1] + kk * 32);
            ax0 = MFMA16(a, w0v, ax0);
            ax1 = MFMA16(a, w1v, ax1);
        }
        if (t > 0) {
            const float* ht = hp + (size_t)(t - 1) * Hz;
#pragma unroll 4
            for (int kk = 0; kk < Hz / 32; ++kk) {
                f32x4 va = *(const f32x4*)(ht + kk * 32);
                f32x4 vb = *(const f32x4*)(ht + kk * 32 + 4);
                bf16x8 a;
#pragma unroll
                for (int e = 0; e < 4; ++e) { a[e] = (__bf16)va[e]; a[4 + e] = (__bf16)vb[e]; }
                bf16x8 w0v = *(const bf16x8*)(whp[0] + kk * 32);
                bf16x8 w1v = *(const bf16x8*)(whp[1] + kk * 32);
                ax0 = MFMA16(a, w0v, ax0);
                ax1 = MFMA16(a, w1v, ax1);
            }
        }
#pragma unroll
        for (int r = 0; r < 4; ++r) {
            int m = wave * 16 + lg * 4 + r;
            zbuf[m * 33 + l15]      = ax0[r];
            zbuf[m * 33 + 16 + l15] = ax1[r];
        }
        __syncthreads();
        {
            float zi = zbuf[gB0*33 + gJ0], zf = zbuf[gB0*33 + 8 + gJ0];
            float zo = zbuf[gB0*33 + 16 + gJ0], zg = zbuf[gB0*33 + 24 + gJ0];
            float cn = sigm(zf) * cs0 + sigm(zi) * tanhf(zg);
            float hn = sigm(zo) * tanhf(cn);
            cs0 = cn;
            out[((size_t)gB0 * Tz + t) * Hz + j0 + gJ0] = hn;
        }
        {
            float zi = zbuf[gB1*33 + gJ1], zf = zbuf[gB1*33 + 8 + gJ1];
            float zo = zbuf[gB1*33 + 16 + gJ1], zg = zbuf[gB1*33 + 24 + gJ1];
            float cn = sigm(zf) * cs1 + sigm(zi) * tanhf(zg);
            float hn = sigm(zo) * tanhf(cn);
            cs1 = cn;
            out[((size_t)gB1 * Tz + t) * Hz + j0 + gJ1] = hn;
        }
        if (s < Tz) bar_arrive(cnt1);                            // publish out[t]
    }
}

extern "C" __global__ void __launch_bounds__(256, 1)
lstm2(const float* __restrict__ x,
      const float* __restrict__ b0,
      const float* __restrict__ b1,
      __bf16* ws,
      float* out)
{
    extern __shared__ char lds_raw[];
    float*  zbuf  = (float*)lds_raw;
    __bf16* wtile = (__bf16*)(lds_raw + ZBUF_BYTES);
    unsigned* cnt0 = (unsigned*)((char*)ws + OFF_BAR * 2);
    unsigned* cnt1 = (unsigned*)((char*)ws + OFF_BAR * 2 + 128);

    if (blockIdx.x < NWG0)
        layer0(x, ws + OFF_W0XH, ws + OFF_W0XL, ws + OFF_W0H, b0,
               ws + OFF_Y0, zbuf, wtile, cnt0);
    else
        layer1(ws + OFF_Y0, ws + OFF_W1, b1, out, zbuf, wtile, cnt0, cnt1);
}

extern "C" void kernel_launch(void* const* d_in, const int* in_sizes, int n_in,
                              void* d_out, int out_size, void* d_ws, size_t ws_size,
                              hipStream_t stream)
{
    const float* x  = (const float*)d_in[0];
    const float* W0 = (const float*)d_in[1];
    const float* b0 = (const float*)d_in[2];
    const float* W1 = (const float*)d_in[3];
    const float* b1 = (const float*)d_in[4];
    float* out = (float*)d_out;
    __bf16* ws = (__bf16*)d_ws;

    hipFuncSetAttribute((const void*)lstm2,
                        hipFuncAttributeMaxDynamicSharedMemorySize, (int)LDS_BYTES);

    hipLaunchKernelGGL(prep_split, dim3(2048), dim3(256), 0, stream, W0, W1, ws);

    void* args[] = { (void*)&x, (void*)&b0, (void*)&b1, (void*)&ws, (void*)&out };
    hipLaunchCooperativeKernel(reinterpret_cast<void*>(lstm2),
                               dim3(NWGT), dim3(256), args, LDS_BYTES, stream);
}

// Round 6
// 7696.133 us; speedup vs baseline: 5.7840x; 1.6421x over previous
//
#include <hip/hip_runtime.h>
#include <hip/hip_bf16.h>

typedef __bf16 bf16x8 __attribute__((ext_vector_type(8)));
typedef float  f32x4  __attribute__((ext_vector_type(4)));

#define MFMA16(a, b, c) __builtin_amdgcn_mfma_f32_16x16x32_bf16((a), (b), (c), 0, 0, 0)

static constexpr int Bz = 64, Tz = 512, Dz = 512, Hz = 1024;
static constexpr int NWG0 = 128;   // WGs per layer
static constexpr int NWGT = 256;
static constexpr int NJ   = 8;     // h-columns per WG

// LDS weight-tile pitches (bf16 elements), +8 pad
static constexpr int PXL = 512 + 8;
static constexpr int PHL = 1024 + 8;
static constexpr int ZBUF_BYTES = 2048 * 4;   // 8 KB, XOR-swizzled [64 b][32 zcol]
static constexpr size_t LDS_BYTES = ZBUF_BYTES + (size_t)(2 * 32 * PXL + 32 * PHL) * 2; // 140800

// ws layout, in bf16 elements
static constexpr size_t N_W0X = 4096ull * 512;
static constexpr size_t N_W0H = 4096ull * 1024;
static constexpr size_t N_W1  = 4096ull * 2048;
static constexpr size_t N_Y0  = 64ull * 512 * 1024;
static constexpr size_t OFF_W0XH = 0;
static constexpr size_t OFF_W0XL = OFF_W0XH + N_W0X;
static constexpr size_t OFF_W0H  = OFF_W0XL + N_W0X;
static constexpr size_t OFF_W1   = OFF_W0H  + N_W0H;
static constexpr size_t OFF_Y0   = OFF_W1   + N_W1;
// flags region (bytes), 256B-aligned: flags0[128] u32, flags1[128] u32
static constexpr size_t FLAGS_BYTE = (((OFF_Y0 + N_Y0) * 2) + 255) & ~(size_t)255;
static constexpr size_t H1S_BYTE   = FLAGS_BYTE + 1024;              // bf16 [64][512][1024] shadow
static constexpr size_t WS_NEED    = H1S_BYTE + N_Y0 * 2;

__device__ __forceinline__ float sigm(float x) { return 1.0f / (1.0f + __expf(-x)); }

// swizzled zbuf index: write (MFMA frag) and read (gate) are both exactly 2-way
__device__ __forceinline__ int zidx(int b, int j, int g)
{
    int raw = (b & 15) | (((j >> 1) & 3) << 4) | ((j & 1) << 6) | (g << 7) | ((b >> 4) << 9);
    return raw ^ ((raw >> 6) & 3);
}

__device__ __forceinline__ void st_agent_u32(void* p, unsigned v)
{ __hip_atomic_store((unsigned*)p, v, __ATOMIC_RELAXED, __HIP_MEMORY_SCOPE_AGENT); }
__device__ __forceinline__ void st_agent_u64(void* p, unsigned long long v)
{ __hip_atomic_store((unsigned long long*)p, v, __ATOMIC_RELAXED, __HIP_MEMORY_SCOPE_AGENT); }

// ---------------- prep: split/cast weights to bf16 in ws; zero flags ----------------
extern "C" __global__ void prep_split(const float* __restrict__ W0,
                                      const float* __restrict__ W1,
                                      __bf16* __restrict__ ws)
{
    if (blockIdx.x == 0 && threadIdx.x < 256)
        ((unsigned*)((char*)ws + FLAGS_BYTE))[threadIdx.x] = 0u;

    __bf16* w0xh = ws + OFF_W0XH;
    __bf16* w0xl = ws + OFF_W0XL;
    __bf16* w0h  = ws + OFF_W0H;
    __bf16* w1c  = ws + OFF_W1;
    const size_t ntot = N_W0X + N_W0H + N_W1;
    for (size_t idx = (size_t)blockIdx.x * blockDim.x + threadIdx.x;
         idx < ntot; idx += (size_t)gridDim.x * blockDim.x) {
        if (idx < N_W0X) {
            size_t r = idx >> 9, c = idx & 511;
            float w = W0[r * 1536 + c];
            __bf16 hi = (__bf16)w;
            w0xh[idx] = hi;
            w0xl[idx] = (__bf16)(w - (float)hi);
        } else if (idx < N_W0X + N_W0H) {
            size_t i = idx - N_W0X;
            size_t r = i >> 10, c = i & 1023;
            w0h[i] = (__bf16)W0[r * 1536 + 512 + c];
        } else {
            size_t i = idx - N_W0X - N_W0H;
            w1c[i] = (__bf16)W1[i];
        }
    }
}

// ---------------- flag-array barrier ----------------
// arrive: one sc1 store of the step number to this WG's own word (no RMW).
// __syncthreads() before it drains vmcnt for every wave -> all agent-scope data
// stores are at the coherence point before the flag becomes observable.
__device__ __forceinline__ void flag_publish(unsigned* flags, int wg, unsigned val)
{
    __syncthreads();
    if (threadIdx.x == 0) st_agent_u32(&flags[wg], val);
}

// wait until all 128 flags >= target (wave 0 polls, lanes cover 2 words each)
__device__ __forceinline__ void wait_flags128(const unsigned* flags, unsigned target)
{
    if (threadIdx.x < 64) {
        const unsigned* p1 = flags + threadIdx.x;
        const unsigned* p2 = p1 + 64;
        for (;;) {
            unsigned a = __hip_atomic_load(p1, __ATOMIC_RELAXED, __HIP_MEMORY_SCOPE_AGENT);
            unsigned b = __hip_atomic_load(p2, __ATOMIC_RELAXED, __HIP_MEMORY_SCOPE_AGENT);
            if (__all(a >= target && b >= target)) break;
            __builtin_amdgcn_s_sleep(2);
        }
    }
    __syncthreads();
    asm volatile("" ::: "memory");
}

// x-part GEMM for one step (hi/lo split on the fly); weights from LDS
__device__ __forceinline__ void zx_compute(const float* __restrict__ xt,
    const __bf16* wxh0, const __bf16* wxl0,
    const __bf16* wxh1, const __bf16* wxl1,
    f32x4& zx0, f32x4& zx1)
{
    f32x4 a0 = {0,0,0,0}, a1 = {0,0,0,0};
#pragma unroll 4
    for (int kk = 0; kk < Dz / 32; ++kk) {
        f32x4 va = *(const f32x4*)(xt + kk * 32);
        f32x4 vb = *(const f32x4*)(xt + kk * 32 + 4);
        bf16x8 ahi, alo;
#pragma unroll
        for (int e = 0; e < 4; ++e) {
            float v = va[e]; __bf16 h1 = (__bf16)v;
            ahi[e] = h1; alo[e] = (__bf16)(v - (float)h1);
            float w = vb[e]; __bf16 h2 = (__bf16)w;
            ahi[4 + e] = h2; alo[4 + e] = (__bf16)(w - (float)h2);
        }
        bf16x8 wh0 = *(const bf16x8*)(wxh0 + kk * 32);
        bf16x8 wl0 = *(const bf16x8*)(wxl0 + kk * 32);
        bf16x8 wh1 = *(const bf16x8*)(wxh1 + kk * 32);
        bf16x8 wl1 = *(const bf16x8*)(wxl1 + kk * 32);
        a0 = MFMA16(ahi, wh0, a0); a0 = MFMA16(alo, wh0, a0); a0 = MFMA16(ahi, wl0, a0);
        a1 = MFMA16(ahi, wh1, a1); a1 = MFMA16(alo, wh1, a1); a1 = MFMA16(ahi, wl1, a1);
    }
    zx0 = a0; zx1 = a1;
}

// ---------------- layer 0 (WGs [0,128)) ----------------
__device__ __forceinline__ void layer0(
    const float* __restrict__ x,
    const __bf16* __restrict__ w0xh, const __bf16* __restrict__ w0xl,
    const __bf16* __restrict__ w0h,  const float* __restrict__ b0,
    __bf16* y0, float* zbuf, __bf16* wtile, unsigned* flags0)
{
    const int tid  = threadIdx.x;
    const int wave = tid >> 6, lane = tid & 63, l15 = lane & 15, lg = lane >> 4;
    const int wg   = blockIdx.x;
    const int j0   = wg * NJ;

    // ---- stage weight slice into LDS (once) ----
    __bf16* sWXH = wtile;
    __bf16* sWXL = wtile + 32 * PXL;
    __bf16* sWH  = wtile + 64 * PXL;
    for (int idx = tid; idx < 32 * (Dz / 8); idx += 256) {
        int r = idx >> 6, kc = (idx & 63) * 8;
        size_t grow = (size_t)((r >> 3) * Hz + j0 + (r & 7));
        *(bf16x8*)(sWXH + r * PXL + kc) = *(const bf16x8*)(w0xh + grow * Dz + kc);
        *(bf16x8*)(sWXL + r * PXL + kc) = *(const bf16x8*)(w0xl + grow * Dz + kc);
    }
    for (int idx = tid; idx < 32 * (Hz / 8); idx += 256) {
        int r = idx >> 7, kc = (idx & 127) * 8;
        size_t grow = (size_t)((r >> 3) * Hz + j0 + (r & 7));
        *(bf16x8*)(sWH + r * PHL + kc) = *(const bf16x8*)(w0h + grow * Hz + kc);
    }
    __syncthreads();

    const __bf16* wxh[2]; const __bf16* wxl[2]; const __bf16* whp[2]; float bv[2];
#pragma unroll
    for (int tn = 0; tn < 2; ++tn) {
        int c = tn * 16 + l15;
        wxh[tn] = sWXH + c * PXL + lg * 8;
        wxl[tn] = sWXL + c * PXL + lg * 8;
        whp[tn] = sWH  + c * PHL + lg * 8;
        bv[tn]  = b0[(c >> 3) * Hz + j0 + (c & 7)];
    }
    const int bA = wave * 16 + l15;
    const float*  xp = x  + (size_t)bA * Tz * Dz + lg * 8;
    const __bf16* hp = y0 + (size_t)bA * Tz * Hz + lg * 8;

    const int gB = tid >> 2;                 // this thread's batch row
    const int gJ = (2 * tid) & 7;            // even col; owns (gJ, gJ+1)
    float cs0 = 0.f, cs1 = 0.f;

    f32x4 zx0, zx1;
    zx_compute(xp, wxh[0], wxl[0], wxh[1], wxl[1], zx0, zx1);   // t = 0

    for (int s = 0; s < Tz; ++s) {
        f32x4 ah0 = {0,0,0,0}, ah1 = {0,0,0,0};
        if (s > 0) {
            wait_flags128(flags0, (unsigned)s);                  // y0[s-1] visible
            const __bf16* ht = hp + (size_t)(s - 1) * Hz;
#pragma unroll 8
            for (int kk = 0; kk < Hz / 32; ++kk) {
                bf16x8 a   = *(const bf16x8*)(ht + kk * 32);
                bf16x8 w0v = *(const bf16x8*)(whp[0] + kk * 32);
                bf16x8 w1v = *(const bf16x8*)(whp[1] + kk * 32);
                ah0 = MFMA16(a, w0v, ah0);
                ah1 = MFMA16(a, w1v, ah1);
            }
        }
#pragma unroll
        for (int r = 0; r < 4; ++r) {
            int m = wave * 16 + lg * 4 + r;
            zbuf[zidx(m, l15 & 7, (l15 >> 3))]     = zx0[r] + ah0[r] + bv[0];
            zbuf[zidx(m, l15 & 7, 2 + (l15 >> 3))] = zx1[r] + ah1[r] + bv[1];
        }
        __syncthreads();
        float zi0 = zbuf[zidx(gB, gJ, 0)],     zf0 = zbuf[zidx(gB, gJ, 1)];
        float zo0 = zbuf[zidx(gB, gJ, 2)],     zg0 = zbuf[zidx(gB, gJ, 3)];
        float zi1 = zbuf[zidx(gB, gJ + 1, 0)], zf1 = zbuf[zidx(gB, gJ + 1, 1)];
        float zo1 = zbuf[zidx(gB, gJ + 1, 2)], zg1 = zbuf[zidx(gB, gJ + 1, 3)];
        float cn0 = sigm(zf0) * cs0 + sigm(zi0) * tanhf(zg0);
        float hn0 = sigm(zo0) * tanhf(cn0);  cs0 = cn0;
        float cn1 = sigm(zf1) * cs1 + sigm(zi1) * tanhf(zg1);
        float hn1 = sigm(zo1) * tanhf(cn1);  cs1 = cn1;
        union { __bf16 h[2]; unsigned u; } pk;
        pk.h[0] = (__bf16)hn0; pk.h[1] = (__bf16)hn1;
        st_agent_u32(&y0[((size_t)gB * Tz + s) * Hz + j0 + gJ], pk.u);

        flag_publish(flags0, wg, (unsigned)(s + 1));             // publish y0[s]
        if (s < Tz - 1)                                          // shadow: x-part of t=s+1
            zx_compute(xp + (size_t)(s + 1) * Dz, wxh[0], wxl[0], wxh[1], wxl[1], zx0, zx1);
    }
}

// ---------------- layer 1 (WGs [128,256)), trails layer 0 ----------------
__device__ __forceinline__ void layer1(
    const __bf16* __restrict__ y0, const __bf16* __restrict__ w1c,
    const float* __restrict__ b1, float* out, __bf16* h1s,
    float* zbuf, __bf16* wtile, unsigned* flags0, unsigned* flags1)
{
    const int tid  = threadIdx.x;
    const int wave = tid >> 6, lane = tid & 63, l15 = lane & 15, lg = lane >> 4;
    const int wg   = blockIdx.x - NWG0;
    const int j0   = wg * NJ;

    // ---- stage weight slice into LDS (once) ----
    __bf16* sWX = wtile;
    __bf16* sWH = wtile + 32 * PHL;
    for (int idx = tid; idx < 32 * (Hz / 8); idx += 256) {
        int r = idx >> 7, kc = (idx & 127) * 8;
        size_t grow = (size_t)((r >> 3) * Hz + j0 + (r & 7));
        const __bf16* srow = w1c + grow * 2048;
        *(bf16x8*)(sWX + r * PHL + kc) = *(const bf16x8*)(srow + kc);
        *(bf16x8*)(sWH + r * PHL + kc) = *(const bf16x8*)(srow + 1024 + kc);
    }
    __syncthreads();

    const __bf16* wxp[2]; const __bf16* whp[2]; float bv[2];
#pragma unroll
    for (int tn = 0; tn < 2; ++tn) {
        int c = tn * 16 + l15;
        wxp[tn] = sWX + c * PHL + lg * 8;
        whp[tn] = sWH + c * PHL + lg * 8;
        bv[tn]  = b1[(c >> 3) * Hz + j0 + (c & 7)];
    }
    const int bA = wave * 16 + l15;
    const __bf16* xp  = y0  + (size_t)bA * Tz * Hz + lg * 8;
    const float*  hpf = out + (size_t)bA * Tz * Hz + lg * 8;
    const __bf16* hps = h1s ? h1s + (size_t)bA * Tz * Hz + lg * 8 : nullptr;

    const int gB = tid >> 2;
    const int gJ = (2 * tid) & 7;
    float cs0 = 0.f, cs1 = 0.f;

    for (int s = 1; s <= Tz; ++s) {
        wait_flags128(flags0, (unsigned)s);                      // y0[s-1] ready
        if (s >= 2) wait_flags128(flags1, (unsigned)(s - 1));    // h1[s-2] ready

        const int t = s - 1;
        f32x4 ax0 = {bv[0], bv[0], bv[0], bv[0]};
        f32x4 ax1 = {bv[1], bv[1], bv[1], bv[1]};

        const __bf16* xt = xp + (size_t)t * Hz;
#pragma unroll 8
        for (int kk = 0; kk < Hz / 32; ++kk) {
            bf16x8 a   = *(const bf16x8*)(xt + kk * 32);
            bf16x8 w0v = *(const bf16x8*)(wxp[0] + kk * 32);
            bf16x8 w1v = *(const bf16x8*)(wxp[1] + kk * 32);
            ax0 = MFMA16(a, w0v, ax0);
            ax1 = MFMA16(a, w1v, ax1);
        }
        if (t > 0) {
            if (hps) {
                const __bf16* ht = hps + (size_t)(t - 1) * Hz;
#pragma unroll 8
                for (int kk = 0; kk < Hz / 32; ++kk) {
                    bf16x8 a   = *(const bf16x8*)(ht + kk * 32);
                    bf16x8 w0v = *(const bf16x8*)(whp[0] + kk * 32);
                    bf16x8 w1v = *(const bf16x8*)(whp[1] + kk * 32);
                    ax0 = MFMA16(a, w0v, ax0);
                    ax1 = MFMA16(a, w1v, ax1);
                }
            } else {
                const float* ht = hpf + (size_t)(t - 1) * Hz;
#pragma unroll 4
                for (int kk = 0; kk < Hz / 32; ++kk) {
                    f32x4 va = *(const f32x4*)(ht + kk * 32);
                    f32x4 vb = *(const f32x4*)(ht + kk * 32 + 4);
                    bf16x8 a;
#pragma unroll
                    for (int e = 0; e < 4; ++e) { a[e] = (__bf16)va[e]; a[4 + e] = (__bf16)vb[e]; }
                    bf16x8 w0v = *(const bf16x8*)(whp[0] + kk * 32);
                    bf16x8 w1v = *(const bf16x8*)(whp[1] + kk * 32);
                    ax0 = MFMA16(a, w0v, ax0);
                    ax1 = MFMA16(a, w1v, ax1);
                }
            }
        }
#pragma unroll
        for (int r = 0; r < 4; ++r) {
            int m = wave * 16 + lg * 4 + r;
            zbuf[zidx(m, l15 & 7, (l15 >> 3))]     = ax0[r];
            zbuf[zidx(m, l15 & 7, 2 + (l15 >> 3))] = ax1[r];
        }
        __syncthreads();
        float zi0 = zbuf[zidx(gB, gJ, 0)],     zf0 = zbuf[zidx(gB, gJ, 1)];
        float zo0 = zbuf[zidx(gB, gJ, 2)],     zg0 = zbuf[zidx(gB, gJ, 3)];
        float zi1 = zbuf[zidx(gB, gJ + 1, 0)], zf1 = zbuf[zidx(gB, gJ + 1, 1)];
        float zo1 = zbuf[zidx(gB, gJ + 1, 2)], zg1 = zbuf[zidx(gB, gJ + 1, 3)];
        float cn0 = sigm(zf0) * cs0 + sigm(zi0) * tanhf(zg0);
        float hn0 = sigm(zo0) * tanhf(cn0);  cs0 = cn0;
        float cn1 = sigm(zf1) * cs1 + sigm(zi1) * tanhf(zg1);
        float hn1 = sigm(zo1) * tanhf(cn1);  cs1 = cn1;

        size_t orow = ((size_t)gB * Tz + t) * Hz + j0 + gJ;
        union { float f[2]; unsigned long long u; } pf;
        pf.f[0] = hn0; pf.f[1] = hn1;
        st_agent_u64(&out[orow], pf.u);
        if (h1s) {
            union { __bf16 h[2]; unsigned u; } pk;
            pk.h[0] = (__bf16)hn0; pk.h[1] = (__bf16)hn1;
            st_agent_u32(&h1s[orow], pk.u);
        }
        if (s < Tz) flag_publish(flags1, wg, (unsigned)s);       // publish h1[t]
    }
}

extern "C" __global__ void __launch_bounds__(256, 1)
lstm2(const float* __restrict__ x,
      const float* __restrict__ b0,
      const float* __restrict__ b1,
      __bf16* ws,
      float* out,
      __bf16* h1s)
{
    extern __shared__ char lds_raw[];
    float*  zbuf  = (float*)lds_raw;
    __bf16* wtile = (__bf16*)(lds_raw + ZBUF_BYTES);
    unsigned* flags0 = (unsigned*)((char*)ws + FLAGS_BYTE);
    unsigned* flags1 = (unsigned*)((char*)ws + FLAGS_BYTE + 512);

    if (blockIdx.x < NWG0)
        layer0(x, ws + OFF_W0XH, ws + OFF_W0XL, ws + OFF_W0H, b0,
               ws + OFF_Y0, zbuf, wtile, flags0);
    else
        layer1(ws + OFF_Y0, ws + OFF_W1, b1, out, h1s, zbuf, wtile, flags0, flags1);
}

extern "C" void kernel_launch(void* const* d_in, const int* in_sizes, int n_in,
                              void* d_out, int out_size, void* d_ws, size_t ws_size,
                              hipStream_t stream)
{
    const float* x  = (const float*)d_in[0];
    const float* W0 = (const float*)d_in[1];
    const float* b0 = (const float*)d_in[2];
    const float* W1 = (const float*)d_in[3];
    const float* b1 = (const float*)d_in[4];
    float* out = (float*)d_out;
    __bf16* ws = (__bf16*)d_ws;
    __bf16* h1s = (ws_size >= WS_NEED) ? (__bf16*)((char*)ws + H1S_BYTE) : nullptr;

    hipFuncSetAttribute((const void*)lstm2,
                        hipFuncAttributeMaxDynamicSharedMemorySize, (int)LDS_BYTES);

    hipLaunchKernelGGL(prep_split, dim3(2048), dim3(256), 0, stream, W0, W1, ws);

    void* args[] = { (void*)&x, (void*)&b0, (void*)&b1, (void*)&ws, (void*)&out, (void*)&h1s };
    hipLaunchCooperativeKernel(reinterpret_cast<void*>(lstm2),
                               dim3(NWGT), dim3(256), args, LDS_BYTES, stream);
}

// Round 9
// 6418.246 us; speedup vs baseline: 6.9357x; 1.1991x over previous
//
#include <hip/hip_runtime.h>
#include <hip/hip_bf16.h>

typedef __bf16 bf16x8 __attribute__((ext_vector_type(8)));
typedef float  f32x4  __attribute__((ext_vector_type(4)));

#define MFMA16(a, b, c) __builtin_amdgcn_mfma_f32_16x16x32_bf16((a), (b), (c), 0, 0, 0)

static constexpr int Bz = 64, Tz = 512, Dz = 512, Hz = 1024;
static constexpr int NWG0 = 128;   // WGs per layer
static constexpr int NWGT = 256;
static constexpr int NJ   = 8;     // h-columns per WG

// LDS weight-tile pitches (bf16 elements), +8 pad
static constexpr int PXL = 512 + 8;
static constexpr int PHL = 1024 + 8;
static constexpr int ZBUF_BYTES = 2048 * 4;   // 8 KB, XOR-swizzled [64 b][32 zcol]
static constexpr size_t LDS_BYTES = ZBUF_BYTES + (size_t)(2 * 32 * PXL + 32 * PHL) * 2; // 140800

// ws layout, in bf16 elements
static constexpr size_t N_W0X = 4096ull * 512;
static constexpr size_t N_W0H = 4096ull * 1024;
static constexpr size_t N_W1  = 4096ull * 2048;
static constexpr size_t N_Y0  = 64ull * 512 * 1024;
static constexpr size_t OFF_W0XH = 0;
static constexpr size_t OFF_W0XL = OFF_W0XH + N_W0X;
static constexpr size_t OFF_W0H  = OFF_W0XL + N_W0X;
static constexpr size_t OFF_W1   = OFF_W0H  + N_W0H;
static constexpr size_t OFF_Y0   = OFF_W1   + N_W1;
static constexpr size_t FLAGS_BYTE = (((OFF_Y0 + N_Y0) * 2) + 255) & ~(size_t)255;
static constexpr size_t H1S_BYTE   = FLAGS_BYTE + 1024;
static constexpr size_t WS_NEED    = H1S_BYTE + N_Y0 * 2;

__device__ __forceinline__ float sigm(float x) { return 1.0f / (1.0f + __expf(-x)); }

// swizzled zbuf index: write (MFMA frag) and read (gate) are both exactly 2-way
__device__ __forceinline__ int zidx(int b, int j, int g)
{
    int raw = (b & 15) | (((j >> 1) & 3) << 4) | ((j & 1) << 6) | (g << 7) | ((b >> 4) << 9);
    return raw ^ ((raw >> 6) & 3);
}

__device__ __forceinline__ void st_agent_u32(void* p, unsigned v)
{ __hip_atomic_store((unsigned*)p, v, __ATOMIC_RELAXED, __HIP_MEMORY_SCOPE_AGENT); }
__device__ __forceinline__ void st_agent_u64(void* p, unsigned long long v)
{ __hip_atomic_store((unsigned long long*)p, v, __ATOMIC_RELAXED, __HIP_MEMORY_SCOPE_AGENT); }

// ---------------- prep: split/cast weights to bf16 in ws; zero flags ----------------
extern "C" __global__ void prep_split(const float* __restrict__ W0,
                                      const float* __restrict__ W1,
                                      __bf16* __restrict__ ws)
{
    if (blockIdx.x == 0 && threadIdx.x < 256)
        ((unsigned*)((char*)ws + FLAGS_BYTE))[threadIdx.x] = 0u;

    __bf16* w0xh = ws + OFF_W0XH;
    __bf16* w0xl = ws + OFF_W0XL;
    __bf16* w0h  = ws + OFF_W0H;
    __bf16* w1c  = ws + OFF_W1;
    const size_t ntot = N_W0X + N_W0H + N_W1;
    for (size_t idx = (size_t)blockIdx.x * blockDim.x + threadIdx.x;
         idx < ntot; idx += (size_t)gridDim.x * blockDim.x) {
        if (idx < N_W0X) {
            size_t r = idx >> 9, c = idx & 511;
            float w = W0[r * 1536 + c];
            __bf16 hi = (__bf16)w;
            w0xh[idx] = hi;
            w0xl[idx] = (__bf16)(w - (float)hi);
        } else if (idx < N_W0X + N_W0H) {
            size_t i = idx - N_W0X;
            size_t r = i >> 10, c = i & 1023;
            w0h[i] = (__bf16)W0[r * 1536 + 512 + c];
        } else {
            size_t i = idx - N_W0X - N_W0H;
            w1c[i] = (__bf16)W1[i];
        }
    }
}

// ---------------- sync primitives ----------------
// publish: __syncthreads drains all waves' agent data stores (vmcnt) -> then one
// agent-scope flag store. Readers only touch monotonically fresh addresses, so no
// stale-cache hazard (validated rounds 4-6).
__device__ __forceinline__ void flag_publish(unsigned* flags, int wg, unsigned val)
{
    __syncthreads();
    if (threadIdx.x == 0) st_agent_u32(&flags[wg], val);
}

// per-wave chunk wait: 32 producer flags (one 128B line); all waves call independently
__device__ __forceinline__ void wait_chunk32(const unsigned* flags, int base, unsigned target)
{
    const unsigned* p = flags + base + (threadIdx.x & 31);
    for (;;) {
        unsigned v = __hip_atomic_load(p, __ATOMIC_RELAXED, __HIP_MEMORY_SCOPE_AGENT);
        if (__all(v >= target)) break;
        __builtin_amdgcn_s_sleep(1);
    }
    asm volatile("" ::: "memory");
}

// x-part GEMM for one step (hi/lo split on the fly); weights from LDS
__device__ __forceinline__ void zx_compute(const float* __restrict__ xt,
    const __bf16* wxh0, const __bf16* wxl0,
    const __bf16* wxh1, const __bf16* wxl1,
    f32x4& zx0, f32x4& zx1)
{
    f32x4 a0 = {0,0,0,0}, a1 = {0,0,0,0};
#pragma unroll 4
    for (int kk = 0; kk < Dz / 32; ++kk) {
        f32x4 va = *(const f32x4*)(xt + kk * 32);
        f32x4 vb = *(const f32x4*)(xt + kk * 32 + 4);
        bf16x8 ahi, alo;
#pragma unroll
        for (int e = 0; e < 4; ++e) {
            float v = va[e]; __bf16 h1 = (__bf16)v;
            ahi[e] = h1; alo[e] = (__bf16)(v - (float)h1);
            float w = vb[e]; __bf16 h2 = (__bf16)w;
            ahi[4 + e] = h2; alo[4 + e] = (__bf16)(w - (float)h2);
        }
        bf16x8 wh0 = *(const bf16x8*)(wxh0 + kk * 32);
        bf16x8 wl0 = *(const bf16x8*)(wxl0 + kk * 32);
        bf16x8 wh1 = *(const bf16x8*)(wxh1 + kk * 32);
        bf16x8 wl1 = *(const bf16x8*)(wxl1 + kk * 32);
        a0 = MFMA16(ahi, wh0, a0); a0 = MFMA16(alo, wh0, a0); a0 = MFMA16(ahi, wl0, a0);
        a1 = MFMA16(ahi, wh1, a1); a1 = MFMA16(alo, wh1, a1); a1 = MFMA16(ahi, wl1, a1);
    }
    zx0 = a0; zx1 = a1;
}

// ---------------- layer 0 (WGs [0,128)) ----------------
__device__ __forceinline__ void layer0(
    const float* __restrict__ x,
    const __bf16* __restrict__ w0xh, const __bf16* __restrict__ w0xl,
    const __bf16* __restrict__ w0h,  const float* __restrict__ b0,
    __bf16* y0, float* zbuf, __bf16* wtile, unsigned* flags0)
{
    const int tid  = threadIdx.x;
    const int wave = tid >> 6, lane = tid & 63, l15 = lane & 15, lg = lane >> 4;
    const int wg   = blockIdx.x;
    const int j0   = wg * NJ;

    // ---- stage weight slice into LDS (once) ----
    __bf16* sWXH = wtile;
    __bf16* sWXL = wtile + 32 * PXL;
    __bf16* sWH  = wtile + 64 * PXL;
    for (int idx = tid; idx < 32 * (Dz / 8); idx += 256) {
        int r = idx >> 6, kc = (idx & 63) * 8;
        size_t grow = (size_t)((r >> 3) * Hz + j0 + (r & 7));
        *(bf16x8*)(sWXH + r * PXL + kc) = *(const bf16x8*)(w0xh + grow * Dz + kc);
        *(bf16x8*)(sWXL + r * PXL + kc) = *(const bf16x8*)(w0xl + grow * Dz + kc);
    }
    for (int idx = tid; idx < 32 * (Hz / 8); idx += 256) {
        int r = idx >> 7, kc = (idx & 127) * 8;
        size_t grow = (size_t)((r >> 3) * Hz + j0 + (r & 7));
        *(bf16x8*)(sWH + r * PHL + kc) = *(const bf16x8*)(w0h + grow * Hz + kc);
    }
    __syncthreads();

    const __bf16* wxh[2]; const __bf16* wxl[2]; const __bf16* whp[2]; float bv[2];
#pragma unroll
    for (int tn = 0; tn < 2; ++tn) {
        int c = tn * 16 + l15;
        wxh[tn] = sWXH + c * PXL + lg * 8;
        wxl[tn] = sWXL + c * PXL + lg * 8;
        whp[tn] = sWH  + c * PHL + lg * 8;
        bv[tn]  = b0[(c >> 3) * Hz + j0 + (c & 7)];
    }
    const int bA = wave * 16 + l15;
    const float*  xp = x  + (size_t)bA * Tz * Dz + lg * 8;
    const __bf16* hp = y0 + (size_t)bA * Tz * Hz + lg * 8;

    const int gB = tid >> 2;                 // this thread's batch row
    const int gJ = (2 * tid) & 7;            // even col; owns (gJ, gJ+1)
    float cs0 = 0.f, cs1 = 0.f;

    f32x4 zx0, zx1;
    zx_compute(xp, wxh[0], wxl[0], wxh[1], wxl[1], zx0, zx1);   // t = 0

    for (int s = 0; s < Tz; ++s) {
        f32x4 ah0 = {0,0,0,0}, ah1 = {0,0,0,0};
        if (s > 0) {
            const __bf16* ht = hp + (size_t)(s - 1) * Hz;
            for (int c = 0; c < 4; ++c) {
                wait_chunk32(flags0, 32 * c, (unsigned)s);       // producers of k-chunk c
#pragma unroll
                for (int kk = 8 * c; kk < 8 * c + 8; ++kk) {
                    bf16x8 a = *(const bf16x8*)(ht + kk * 32);
                    ah0 = MFMA16(a, *(const bf16x8*)(whp[0] + kk * 32), ah0);
                    ah1 = MFMA16(a, *(const bf16x8*)(whp[1] + kk * 32), ah1);
                }
            }
        }
#pragma unroll
        for (int r = 0; r < 4; ++r) {
            int m = wave * 16 + lg * 4 + r;
            zbuf[zidx(m, l15 & 7, (l15 >> 3))]     = zx0[r] + ah0[r] + bv[0];
            zbuf[zidx(m, l15 & 7, 2 + (l15 >> 3))] = zx1[r] + ah1[r] + bv[1];
        }
        __syncthreads();
        float zi0 = zbuf[zidx(gB, gJ, 0)],     zf0 = zbuf[zidx(gB, gJ, 1)];
        float zo0 = zbuf[zidx(gB, gJ, 2)],     zg0 = zbuf[zidx(gB, gJ, 3)];
        float zi1 = zbuf[zidx(gB, gJ + 1, 0)], zf1 = zbuf[zidx(gB, gJ + 1, 1)];
        float zo1 = zbuf[zidx(gB, gJ + 1, 2)], zg1 = zbuf[zidx(gB, gJ + 1, 3)];
        float cn0 = sigm(zf0) * cs0 + sigm(zi0) * tanhf(zg0);
        float hn0 = sigm(zo0) * tanhf(cn0);  cs0 = cn0;
        float cn1 = sigm(zf1) * cs1 + sigm(zi1) * tanhf(zg1);
        float hn1 = sigm(zo1) * tanhf(cn1);  cs1 = cn1;
        union { __bf16 h[2]; unsigned u; } pk;
        pk.h[0] = (__bf16)hn0; pk.h[1] = (__bf16)hn1;
        st_agent_u32(&y0[((size_t)gB * Tz + s) * Hz + j0 + gJ], pk.u);

        flag_publish(flags0, wg, (unsigned)(s + 1));             // publish y0[s]
        if (s < Tz - 1)                                          // shadow: x-part of t=s+1
            zx_compute(xp + (size_t)(s + 1) * Dz, wxh[0], wxl[0], wxh[1], wxl[1], zx0, zx1);
    }
}

// ---------------- layer 1 (WGs [128,256)), trails layer 0 ----------------
__device__ __forceinline__ void layer1(
    const __bf16* __restrict__ y0, const __bf16* __restrict__ w1c,
    const float* __restrict__ b1, float* out, __bf16* h1s,
    float* zbuf, __bf16* wtile, unsigned* flags0, unsigned* flags1)
{
    const int tid  = threadIdx.x;
    const int wave = tid >> 6, lane = tid & 63, l15 = lane & 15, lg = lane >> 4;
    const int wg   = blockIdx.x - NWG0;
    const int j0   = wg * NJ;

    // ---- stage weight slice into LDS (once) ----
    __bf16* sWX = wtile;
    __bf16* sWH = wtile + 32 * PHL;
    for (int idx = tid; idx < 32 * (Hz / 8); idx += 256) {
        int r = idx >> 7, kc = (idx & 127) * 8;
        size_t grow = (size_t)((r >> 3) * Hz + j0 + (r & 7));
        const __bf16* srow = w1c + grow * 2048;
        *(bf16x8*)(sWX + r * PHL + kc) = *(const bf16x8*)(srow + kc);
        *(bf16x8*)(sWH + r * PHL + kc) = *(const bf16x8*)(srow + 1024 + kc);
    }
    __syncthreads();

    const __bf16* wxp[2]; const __bf16* whp[2]; float bv[2];
#pragma unroll
    for (int tn = 0; tn < 2; ++tn) {
        int c = tn * 16 + l15;
        wxp[tn] = sWX + c * PHL + lg * 8;
        whp[tn] = sWH + c * PHL + lg * 8;
        bv[tn]  = b1[(c >> 3) * Hz + j0 + (c & 7)];
    }
    const int bA = wave * 16 + l15;
    const __bf16* xp  = y0  + (size_t)bA * Tz * Hz + lg * 8;
    const float*  hpf = out + (size_t)bA * Tz * Hz + lg * 8;
    const __bf16* hps = h1s ? h1s + (size_t)bA * Tz * Hz + lg * 8 : nullptr;

    const int gB = tid >> 2;
    const int gJ = (2 * tid) & 7;
    float cs0 = 0.f, cs1 = 0.f;

    for (int s = 1; s <= Tz; ++s) {
        const int t = s - 1;
        f32x4 ax0 = {bv[0], bv[0], bv[0], bv[0]};
        f32x4 ax1 = {bv[1], bv[1], bv[1], bv[1]};

        // ---- h-part FIRST (own-layer flags, ~already published) so it overlaps
        //      layer-0's publish of y0[s-1] ----
        if (t > 0) {
            if (hps) {
                const __bf16* ht = hps + (size_t)(t - 1) * Hz;
                for (int c = 0; c < 4; ++c) {
                    wait_chunk32(flags1, 32 * c, (unsigned)(s - 1));
#pragma unroll
                    for (int kk = 8 * c; kk < 8 * c + 8; ++kk) {
                        bf16x8 a = *(const bf16x8*)(ht + kk * 32);
                        ax0 = MFMA16(a, *(const bf16x8*)(whp[0] + kk * 32), ax0);
                        ax1 = MFMA16(a, *(const bf16x8*)(whp[1] + kk * 32), ax1);
                    }
                }
            } else {
                const float* ht = hpf + (size_t)(t - 1) * Hz;
                for (int c = 0; c < 4; ++c) {
                    wait_chunk32(flags1, 32 * c, (unsigned)(s - 1));
#pragma unroll
                    for (int kk = 8 * c; kk < 8 * c + 8; ++kk) {
                        f32x4 va = *(const f32x4*)(ht + kk * 32);
                        f32x4 vb = *(const f32x4*)(ht + kk * 32 + 4);
                        bf16x8 a;
#pragma unroll
                        for (int e = 0; e < 4; ++e) { a[e] = (__bf16)va[e]; a[4 + e] = (__bf16)vb[e]; }
                        ax0 = MFMA16(a, *(const bf16x8*)(whp[0] + kk * 32), ax0);
                        ax1 = MFMA16(a, *(const bf16x8*)(whp[1] + kk * 32), ax1);
                    }
                }
            }
        }
        // ---- x-part: consume y0[s-1] chunk-by-chunk as layer-0 flags arrive ----
        {
            const __bf16* xt = xp + (size_t)t * Hz;
            for (int c = 0; c < 4; ++c) {
                wait_chunk32(flags0, 32 * c, (unsigned)s);
#pragma unroll
                for (int kk = 8 * c; kk < 8 * c + 8; ++kk) {
                    bf16x8 a = *(const bf16x8*)(xt + kk * 32);
                    ax0 = MFMA16(a, *(const bf16x8*)(wxp[0] + kk * 32), ax0);
                    ax1 = MFMA16(a, *(const bf16x8*)(wxp[1] + kk * 32), ax1);
                }
            }
        }

#pragma unroll
        for (int r = 0; r < 4; ++r) {
            int m = wave * 16 + lg * 4 + r;
            zbuf[zidx(m, l15 & 7, (l15 >> 3))]     = ax0[r];
            zbuf[zidx(m, l15 & 7, 2 + (l15 >> 3))] = ax1[r];
        }
        __syncthreads();
        float zi0 = zbuf[zidx(gB, gJ, 0)],     zf0 = zbuf[zidx(gB, gJ, 1)];
        float zo0 = zbuf[zidx(gB, gJ, 2)],     zg0 = zbuf[zidx(gB, gJ, 3)];
        float zi1 = zbuf[zidx(gB, gJ + 1, 0)], zf1 = zbuf[zidx(gB, gJ + 1, 1)];
        float zo1 = zbuf[zidx(gB, gJ + 1, 2)], zg1 = zbuf[zidx(gB, gJ + 1, 3)];
        float cn0 = sigm(zf0) * cs0 + sigm(zi0) * tanhf(zg0);
        float hn0 = sigm(zo0) * tanhf(cn0);  cs0 = cn0;
        float cn1 = sigm(zf1) * cs1 + sigm(zi1) * tanhf(zg1);
        float hn1 = sigm(zo1) * tanhf(cn1);  cs1 = cn1;

        size_t orow = ((size_t)gB * Tz + t) * Hz + j0 + gJ;
        union { float f[2]; unsigned long long u; } pf;
        pf.f[0] = hn0; pf.f[1] = hn1;
        st_agent_u64(&out[orow], pf.u);
        if (h1s) {
            union { __bf16 h[2]; unsigned u; } pk;
            pk.h[0] = (__bf16)hn0; pk.h[1] = (__bf16)hn1;
            st_agent_u32(&h1s[orow], pk.u);
        }
        if (s < Tz) flag_publish(flags1, wg, (unsigned)s);       // publish h1[t]
    }
}

extern "C" __global__ void __launch_bounds__(256, 1)
lstm2(const float* __restrict__ x,
      const float* __restrict__ b0,
      const float* __restrict__ b1,
      __bf16* ws,
      float* out,
      __bf16* h1s)
{
    extern __shared__ char lds_raw[];
    float*  zbuf  = (float*)lds_raw;
    __bf16* wtile = (__bf16*)(lds_raw + ZBUF_BYTES);
    unsigned* flags0 = (unsigned*)((char*)ws + FLAGS_BYTE);
    unsigned* flags1 = (unsigned*)((char*)ws + FLAGS_BYTE + 512);

    if (blockIdx.x < NWG0)
        layer0(x, ws + OFF_W0XH, ws + OFF_W0XL, ws + OFF_W0H, b0,
               ws + OFF_Y0, zbuf, wtile, flags0);
    else
        layer1(ws + OFF_Y0, ws + OFF_W1, b1, out, h1s, zbuf, wtile, flags0, flags1);
}

extern "C" void kernel_launch(void* const* d_in, const int* in_sizes, int n_in,
                              void* d_out, int out_size, void* d_ws, size_t ws_size,
                              hipStream_t stream)
{
    const float* x  = (const float*)d_in[0];
    const float* W0 = (const float*)d_in[1];
    const float* b0 = (const float*)d_in[2];
    const float* W1 = (const float*)d_in[3];
    const float* b1 = (const float*)d_in[4];
    float* out = (float*)d_out;
    __bf16* ws = (__bf16*)d_ws;
    __bf16* h1s = (ws_size >= WS_NEED) ? (__bf16*)((char*)ws + H1S_BYTE) : nullptr;

    (void)hipFuncSetAttribute((const void*)lstm2,
                        hipFuncAttributeMaxDynamicSharedMemorySize, (int)LDS_BYTES);

    hipLaunchKernelGGL(prep_split, dim3(2048), dim3(256), 0, stream, W0, W1, ws);

    void* args[] = { (void*)&x, (void*)&b0, (void*)&b1, (void*)&ws, (void*)&out, (void*)&h1s };
    (void)hipLaunchCooperativeKernel(reinterpret_cast<void*>(lstm2),
                               dim3(NWGT), dim3(256), args, LDS_BYTES, stream);
}

// Round 10
// 6076.914 us; speedup vs baseline: 7.3252x; 1.0562x over previous
//
#include <hip/hip_runtime.h>
#include <hip/hip_bf16.h>

typedef __bf16 bf16x8 __attribute__((ext_vector_type(8)));
typedef float  f32x4  __attribute__((ext_vector_type(4)));

#define MFMA16(a, b, c) __builtin_amdgcn_mfma_f32_16x16x32_bf16((a), (b), (c), 0, 0, 0)

static constexpr int Bz = 64, Tz = 512, Dz = 512, Hz = 1024;
static constexpr int NWG0 = 128;   // WGs per layer
static constexpr int NWGT = 256;
static constexpr int NJ   = 8;     // h-columns per WG

// LDS weight-tile pitches (bf16 elements), +8 pad
static constexpr int PXL = 512 + 8;
static constexpr int PHL = 1024 + 8;
static constexpr size_t LDS_BYTES = (size_t)(2 * 32 * PXL + 32 * PHL) * 2;  // 132608

// ws layout, in bf16 elements
static constexpr size_t N_W0X = 4096ull * 512;
static constexpr size_t N_W0H = 4096ull * 1024;
static constexpr size_t N_W1  = 4096ull * 2048;
static constexpr size_t N_Y0  = 64ull * 512 * 1024;
static constexpr size_t OFF_W0XH = 0;
static constexpr size_t OFF_W0XL = OFF_W0XH + N_W0X;
static constexpr size_t OFF_W0H  = OFF_W0XL + N_W0X;
static constexpr size_t OFF_W1   = OFF_W0H  + N_W0H;
static constexpr size_t OFF_Y0   = OFF_W1   + N_W1;
// flags: per (wave,wg): flags0[4][128] u32 (2KB) then flags1[4][128] (2KB)
static constexpr size_t FLAGS_BYTE = (((OFF_Y0 + N_Y0) * 2) + 255) & ~(size_t)255;
static constexpr size_t H1S_BYTE   = FLAGS_BYTE + 4096;
static constexpr size_t WS_NEED    = H1S_BYTE + N_Y0 * 2;

__device__ __forceinline__ float sigm(float x) { return 1.0f / (1.0f + __expf(-x)); }

__device__ __forceinline__ void st_agent_u32(void* p, unsigned v)
{ __hip_atomic_store((unsigned*)p, v, __ATOMIC_RELAXED, __HIP_MEMORY_SCOPE_AGENT); }
__device__ __forceinline__ void st_agent_f32(float* p, float v)
{ __hip_atomic_store(p, v, __ATOMIC_RELAXED, __HIP_MEMORY_SCOPE_AGENT); }

// ---------------- prep: split/cast weights to bf16 in ws; zero flags ----------------
extern "C" __global__ void prep_split(const float* __restrict__ W0,
                                      const float* __restrict__ W1,
                                      __bf16* __restrict__ ws)
{
    if (blockIdx.x == 0)
        for (int i = threadIdx.x; i < 1024; i += 256)
            ((unsigned*)((char*)ws + FLAGS_BYTE))[i] = 0u;

    __bf16* w0xh = ws + OFF_W0XH;
    __bf16* w0xl = ws + OFF_W0XL;
    __bf16* w0h  = ws + OFF_W0H;
    __bf16* w1c  = ws + OFF_W1;
    const size_t ntot = N_W0X + N_W0H + N_W1;
    for (size_t idx = (size_t)blockIdx.x * blockDim.x + threadIdx.x;
         idx < ntot; idx += (size_t)gridDim.x * blockDim.x) {
        if (idx < N_W0X) {
            size_t r = idx >> 9, c = idx & 511;
            float w = W0[r * 1536 + c];
            __bf16 hi = (__bf16)w;
            w0xh[idx] = hi;
            w0xl[idx] = (__bf16)(w - (float)hi);
        } else if (idx < N_W0X + N_W0H) {
            size_t i = idx - N_W0X;
            size_t r = i >> 10, c = i & 1023;
            w0h[i] = (__bf16)W0[r * 1536 + 512 + c];
        } else {
            size_t i = idx - N_W0X - N_W0H;
            w1c[i] = (__bf16)W1[i];
        }
    }
}

// ---------------- sync primitives (per-wave) ----------------
// publish: wave drains its OWN outstanding global stores (vmcnt(0)) -> then one
// relaxed agent-scope flag store. Data stores are agent-scope (write to coherence
// point), flag readers use agent loads; readers touch monotonically fresh
// addresses each step -> no stale-line hazard (validated rounds 4-9).
__device__ __forceinline__ void publish(unsigned* p, unsigned v)
{
    asm volatile("s_waitcnt vmcnt(0)" ::: "memory");
    __hip_atomic_store(p, v, __ATOMIC_RELAXED, __HIP_MEMORY_SCOPE_AGENT);
}

// wave-level wait on 32 producer flags (one 128B line)
__device__ __forceinline__ void wait_chunk32(const unsigned* flags, int base, unsigned target)
{
    const unsigned* p = flags + base + (threadIdx.x & 31);
    for (;;) {
        unsigned v = __hip_atomic_load(p, __ATOMIC_RELAXED, __HIP_MEMORY_SCOPE_AGENT);
        if (__all(v >= target)) break;
        __builtin_amdgcn_s_sleep(1);
    }
    asm volatile("" ::: "memory");
}

// x-part GEMM for one step (hi/lo split on the fly); weights from LDS
__device__ __forceinline__ void zx_compute(const float* __restrict__ xt,
    const __bf16* wxh0, const __bf16* wxl0,
    const __bf16* wxh1, const __bf16* wxl1,
    f32x4& zx0, f32x4& zx1)
{
    f32x4 a0 = {0,0,0,0}, a1 = {0,0,0,0};
#pragma unroll 4
    for (int kk = 0; kk < Dz / 32; ++kk) {
        f32x4 va = *(const f32x4*)(xt + kk * 32);
        f32x4 vb = *(const f32x4*)(xt + kk * 32 + 4);
        bf16x8 ahi, alo;
#pragma unroll
        for (int e = 0; e < 4; ++e) {
            float v = va[e]; __bf16 h1 = (__bf16)v;
            ahi[e] = h1; alo[e] = (__bf16)(v - (float)h1);
            float w = vb[e]; __bf16 h2 = (__bf16)w;
            ahi[4 + e] = h2; alo[4 + e] = (__bf16)(w - (float)h2);
        }
        bf16x8 wh0 = *(const bf16x8*)(wxh0 + kk * 32);
        bf16x8 wl0 = *(const bf16x8*)(wxl0 + kk * 32);
        bf16x8 wh1 = *(const bf16x8*)(wxh1 + kk * 32);
        bf16x8 wl1 = *(const bf16x8*)(wxl1 + kk * 32);
        a0 = MFMA16(ahi, wh0, a0); a0 = MFMA16(alo, wh0, a0); a0 = MFMA16(ahi, wl0, a0);
        a1 = MFMA16(ahi, wh1, a1); a1 = MFMA16(alo, wh1, a1); a1 = MFMA16(ahi, wl1, a1);
    }
    zx0 = a0; zx1 = a1;
}

// in-register gates. D-frag: thread (lg,l15) holds rows 4*lg+r (r=0..3), col l15
// (tile0: gates i|f at j=l15&7) / col 16+l15 (tile1: o|g). Partner lane l15^8 has
// the complementary gate pair for the same j. One shfl_xor(8) -> each lane owns
// 2 complete cells (rows split low/hi). bf16 outputs are lane-pair packed into
// native u32 agent stores (NO 16-bit atomics — round-8 failure suspect).
template <bool F32OUT>
__device__ __forceinline__ void gates_emit(
    f32x4 za, f32x4 zb, float* cs, int l15, int rowBase,
    __bf16* ybf, float* yf32, size_t rowStride)
{
    f32x4 pa, pb;
#pragma unroll
    for (int e = 0; e < 4; ++e) { pa[e] = __shfl_xor(za[e], 8, 64); pb[e] = __shfl_xor(zb[e], 8, 64); }
    const bool hi    = (l15 & 8) != 0;
    const bool evenj = ((l15 & 1) == 0);
#pragma unroll
    for (int k2 = 0; k2 < 2; ++k2) {
        float zi, zf, zo, zg;
        if (hi) { zi = pa[2 + k2]; zf = za[2 + k2]; zo = pb[2 + k2]; zg = zb[2 + k2]; }
        else    { zi = za[k2];     zf = pa[k2];     zo = zb[k2];     zg = pb[k2];     }
        float cn = sigm(zf) * cs[k2] + sigm(zi) * tanhf(zg);
        float hn = sigm(zo) * tanhf(cn);
        cs[k2] = cn;
        int b = rowBase + (hi ? 2 : 0) + k2;
        size_t ofs = (size_t)b * rowStride;
        if (F32OUT) st_agent_f32(&yf32[ofs], hn);
        if (ybf) {
            __bf16 hb = (__bf16)hn;
            unsigned bits = (unsigned)__builtin_bit_cast(unsigned short, hb);
            unsigned par  = __shfl_down(bits, 1, 64);   // partner j+1, same row
            if (evenj) st_agent_u32((unsigned*)(ybf + ofs), bits | (par << 16));
        }
    }
}

// ---------------- layer 0 (WGs [0,128)) ----------------
__device__ __forceinline__ void layer0(
    const float* __restrict__ x,
    const __bf16* __restrict__ w0xh, const __bf16* __restrict__ w0xl,
    const __bf16* __restrict__ w0h,  const float* __restrict__ b0,
    __bf16* y0, __bf16* wtile, unsigned* flags0)
{
    const int tid  = threadIdx.x;
    const int wave = tid >> 6, lane = tid & 63, l15 = lane & 15, lg = lane >> 4;
    const int wg   = blockIdx.x;
    const int j0   = wg * NJ;

    // ---- stage weight slice into LDS (once) ----
    __bf16* sWXH = wtile;
    __bf16* sWXL = wtile + 32 * PXL;
    __bf16* sWH  = wtile + 64 * PXL;
    for (int idx = tid; idx < 32 * (Dz / 8); idx += 256) {
        int r = idx >> 6, kc = (idx & 63) * 8;
        size_t grow = (size_t)((r >> 3) * Hz + j0 + (r & 7));
        *(bf16x8*)(sWXH + r * PXL + kc) = *(const bf16x8*)(w0xh + grow * Dz + kc);
        *(bf16x8*)(sWXL + r * PXL + kc) = *(const bf16x8*)(w0xl + grow * Dz + kc);
    }
    for (int idx = tid; idx < 32 * (Hz / 8); idx += 256) {
        int r = idx >> 7, kc = (idx & 127) * 8;
        size_t grow = (size_t)((r >> 3) * Hz + j0 + (r & 7));
        *(bf16x8*)(sWH + r * PHL + kc) = *(const bf16x8*)(w0h + grow * Hz + kc);
    }
    __syncthreads();   // only barrier: LDS weights ready; waves decouple after this

    const __bf16* wxh[2]; const __bf16* wxl[2]; const __bf16* whp[2]; float bv[2];
#pragma unroll
    for (int tn = 0; tn < 2; ++tn) {
        int c = tn * 16 + l15;
        wxh[tn] = sWXH + c * PXL + lg * 8;
        wxl[tn] = sWXL + c * PXL + lg * 8;
        whp[tn] = sWH  + c * PHL + lg * 8;
        bv[tn]  = b0[(c >> 3) * Hz + j0 + (c & 7)];
    }
    const int bA = wave * 16 + l15;
    const float*  xp = x  + (size_t)bA * Tz * Dz + lg * 8;
    const __bf16* hp = y0 + (size_t)bA * Tz * Hz + lg * 8;

    const unsigned* flw = flags0 + wave * 128;     // this wave's producer row
    unsigned* myflag     = flags0 + wave * 128 + wg;

    float cs[2] = {0.f, 0.f};
    f32x4 zx0, zx1;
    zx_compute(xp, wxh[0], wxl[0], wxh[1], wxl[1], zx0, zx1);   // t = 0

    for (int s = 0; s < Tz; ++s) {
        f32x4 ah0 = {0,0,0,0}, ah1 = {0,0,0,0};
        if (s > 0) {
            const __bf16* ht = hp + (size_t)(s - 1) * Hz;
            for (int c = 0; c < 4; ++c) {
                wait_chunk32(flw, 32 * c, (unsigned)s);          // wave-w producers, chunk c
#pragma unroll
                for (int kk = 8 * c; kk < 8 * c + 8; ++kk) {
                    bf16x8 a = *(const bf16x8*)(ht + kk * 32);
                    ah0 = MFMA16(a, *(const bf16x8*)(whp[0] + kk * 32), ah0);
                    ah1 = MFMA16(a, *(const bf16x8*)(whp[1] + kk * 32), ah1);
                }
            }
        }
        f32x4 za, zb;
#pragma unroll
        for (int e = 0; e < 4; ++e) { za[e] = zx0[e] + ah0[e] + bv[0]; zb[e] = zx1[e] + ah1[e] + bv[1]; }

        gates_emit<false>(za, zb, cs, l15, wave * 16 + lg * 4,
                          y0 + (size_t)s * Hz + j0 + (l15 & 7), nullptr, (size_t)Tz * Hz);

        publish(myflag, (unsigned)(s + 1));                      // this wave's 16 rows ready
        if (s < Tz - 1)                                          // shadow: x-part of t=s+1
            zx_compute(xp + (size_t)(s + 1) * Dz, wxh[0], wxl[0], wxh[1], wxl[1], zx0, zx1);
    }
}

// ---------------- layer 1 (WGs [128,256)), trails layer 0 ----------------
__device__ __forceinline__ void layer1(
    const __bf16* __restrict__ y0, const __bf16* __restrict__ w1c,
    const float* __restrict__ b1, float* out, __bf16* h1s,
    __bf16* wtile, unsigned* flags0, unsigned* flags1)
{
    const int tid  = threadIdx.x;
    const int wave = tid >> 6, lane = tid & 63, l15 = lane & 15, lg = lane >> 4;
    const int wg   = blockIdx.x - NWG0;
    const int j0   = wg * NJ;

    // ---- stage weight slice into LDS (once) ----
    __bf16* sWX = wtile;
    __bf16* sWH = wtile + 32 * PHL;
    for (int idx = tid; idx < 32 * (Hz / 8); idx += 256) {
        int r = idx >> 7, kc = (idx & 127) * 8;
        size_t grow = (size_t)((r >> 3) * Hz + j0 + (r & 7));
        const __bf16* srow = w1c + grow * 2048;
        *(bf16x8*)(sWX + r * PHL + kc) = *(const bf16x8*)(srow + kc);
        *(bf16x8*)(sWH + r * PHL + kc) = *(const bf16x8*)(srow + 1024 + kc);
    }
    __syncthreads();

    const __bf16* wxp[2]; const __bf16* whp[2]; float bv[2];
#pragma unroll
    for (int tn = 0; tn < 2; ++tn) {
        int c = tn * 16 + l15;
        wxp[tn] = sWX + c * PHL + lg * 8;
        whp[tn] = sWH + c * PHL + lg * 8;
        bv[tn]  = b1[(c >> 3) * Hz + j0 + (c & 7)];
    }
    const int bA = wave * 16 + l15;
    const __bf16* xp  = y0  + (size_t)bA * Tz * Hz + lg * 8;
    const float*  hpf = out + (size_t)bA * Tz * Hz + lg * 8;
    const __bf16* hps = h1s ? h1s + (size_t)bA * Tz * Hz + lg * 8 : nullptr;

    const unsigned* fl0w = flags0 + wave * 128;
    const unsigned* fl1w = flags1 + wave * 128;
    unsigned* myflag      = flags1 + wave * 128 + wg;

    float cs[2] = {0.f, 0.f};

    for (int s = 1; s <= Tz; ++s) {
        const int t = s - 1;
        f32x4 ax0 = {bv[0], bv[0], bv[0], bv[0]};
        f32x4 ax1 = {bv[1], bv[1], bv[1], bv[1]};

        // ---- h-part FIRST (own-layer flags, ~already set) ----
        if (t > 0) {
            if (hps) {
                const __bf16* ht = hps + (size_t)(t - 1) * Hz;
                for (int c = 0; c < 4; ++c) {
                    wait_chunk32(fl1w, 32 * c, (unsigned)(s - 1));
#pragma unroll
                    for (int kk = 8 * c; kk < 8 * c + 8; ++kk) {
                        bf16x8 a = *(const bf16x8*)(ht + kk * 32);
                        ax0 = MFMA16(a, *(const bf16x8*)(whp[0] + kk * 32), ax0);
                        ax1 = MFMA16(a, *(const bf16x8*)(whp[1] + kk * 32), ax1);
                    }
                }
            } else {
                const float* ht = hpf + (size_t)(t - 1) * Hz;
                for (int c = 0; c < 4; ++c) {
                    wait_chunk32(fl1w, 32 * c, (unsigned)(s - 1));
#pragma unroll
                    for (int kk = 8 * c; kk < 8 * c + 8; ++kk) {
                        f32x4 va = *(const f32x4*)(ht + kk * 32);
                        f32x4 vb = *(const f32x4*)(ht + kk * 32 + 4);
                        bf16x8 a;
#pragma unroll
                        for (int e = 0; e < 4; ++e) { a[e] = (__bf16)va[e]; a[4 + e] = (__bf16)vb[e]; }
                        ax0 = MFMA16(a, *(const bf16x8*)(whp[0] + kk * 32), ax0);
                        ax1 = MFMA16(a, *(const bf16x8*)(whp[1] + kk * 32), ax1);
                    }
                }
            }
        }
        // ---- x-part: consume y0[s-1] chunk-by-chunk as layer-0 wave flags arrive ----
        {
            const __bf16* xt = xp + (size_t)t * Hz;
            for (int c = 0; c < 4; ++c) {
                wait_chunk32(fl0w, 32 * c, (unsigned)s);
#pragma unroll
                for (int kk = 8 * c; kk < 8 * c + 8; ++kk) {
                    bf16x8 a = *(const bf16x8*)(xt + kk * 32);
                    ax0 = MFMA16(a, *(const bf16x8*)(wxp[0] + kk * 32), ax0);
                    ax1 = MFMA16(a, *(const bf16x8*)(wxp[1] + kk * 32), ax1);
                }
            }
        }

        gates_emit<true>(ax0, ax1, cs, l15, wave * 16 + lg * 4,
                         h1s ? (h1s + (size_t)t * Hz + j0 + (l15 & 7)) : nullptr,
                         out + (size_t)t * Hz + j0 + (l15 & 7),
                         (size_t)Tz * Hz);

        if (s < Tz) publish(myflag, (unsigned)s);                // h1[t] ready (this wave)
    }
}

extern "C" __global__ void __launch_bounds__(256, 1)
lstm2(const float* __restrict__ x,
      const float* __restrict__ b0,
      const float* __restrict__ b1,
      __bf16* ws,
      float* out,
      __bf16* h1s)
{
    extern __shared__ char lds_raw[];
    __bf16* wtile = (__bf16*)lds_raw;
    unsigned* flags0 = (unsigned*)((char*)ws + FLAGS_BYTE);
    unsigned* flags1 = (unsigned*)((char*)ws + FLAGS_BYTE + 2048);

    if (blockIdx.x < NWG0)
        layer0(x, ws + OFF_W0XH, ws + OFF_W0XL, ws + OFF_W0H, b0,
               ws + OFF_Y0, wtile, flags0);
    else
        layer1(ws + OFF_Y0, ws + OFF_W1, b1, out, h1s, wtile, flags0, flags1);
}

extern "C" void kernel_launch(void* const* d_in, const int* in_sizes, int n_in,
                              void* d_out, int out_size, void* d_ws, size_t ws_size,
                              hipStream_t stream)
{
    const float* x  = (const float*)d_in[0];
    const float* W0 = (const float*)d_in[1];
    const float* b0 = (const float*)d_in[2];
    const float* W1 = (const float*)d_in[3];
    const float* b1 = (const float*)d_in[4];
    float* out = (float*)d_out;
    __bf16* ws = (__bf16*)d_ws;
    __bf16* h1s = (ws_size >= WS_NEED) ? (__bf16*)((char*)ws + H1S_BYTE) : nullptr;

    (void)hipFuncSetAttribute((const void*)lstm2,
                        hipFuncAttributeMaxDynamicSharedMemorySize, (int)LDS_BYTES);

    hipLaunchKernelGGL(prep_split, dim3(2048), dim3(256), 0, stream, W0, W1, ws);

    void* args[] = { (void*)&x, (void*)&b0, (void*)&b1, (void*)&ws, (void*)&out, (void*)&h1s };
    (void)hipLaunchCooperativeKernel(reinterpret_cast<void*>(lstm2),
                               dim3(NWGT), dim3(256), args, LDS_BYTES, stream);
}